// Round 1
// baseline (1652.235 us; speedup 1.0000x reference)
//
#include <hip/hip_runtime.h>
#include <math.h>

#define NN 10000
#define NFEAT 512
#define NHID 256
#define NCLASS 40
#define NLAYERS 8
#define MAXDEG 96

// ---------------------------------------------------------------------------
// build_graph: one block per row. One pass over the 400MB dense adjacency:
// collects nonzero column indices into ELL (order irrelevant for the sum)
// and computes d_inv_sqrt[i] = rsqrt(1 + row_nnz)  (A_hat = A + I).
// ---------------------------------------------------------------------------
__global__ __launch_bounds__(256) void build_graph(const float* __restrict__ adj,
                                                   int* __restrict__ cnt,
                                                   int* __restrict__ ell,
                                                   float* __restrict__ dinv) {
    int i = blockIdx.x;
    __shared__ int scnt;
    if (threadIdx.x == 0) scnt = 0;
    __syncthreads();
    const float4* row = (const float4*)(adj + (size_t)i * NN);
    const int nv = NN / 4;  // 2500
    int* erow = ell + (size_t)i * MAXDEG;
    for (int f = threadIdx.x; f < nv; f += 256) {
        float4 v = row[f];
        if (v.x != 0.0f) { int s = atomicAdd(&scnt, 1); if (s < MAXDEG) erow[s] = 4*f + 0; }
        if (v.y != 0.0f) { int s = atomicAdd(&scnt, 1); if (s < MAXDEG) erow[s] = 4*f + 1; }
        if (v.z != 0.0f) { int s = atomicAdd(&scnt, 1); if (s < MAXDEG) erow[s] = 4*f + 2; }
        if (v.w != 0.0f) { int s = atomicAdd(&scnt, 1); if (s < MAXDEG) erow[s] = 4*f + 3; }
    }
    __syncthreads();
    if (threadIdx.x == 0) {
        int c = scnt;
        cnt[i] = (c < MAXDEG) ? c : MAXDEG;
        dinv[i] = rsqrtf(1.0f + (float)c);
    }
}

// ---------------------------------------------------------------------------
// h0 = relu(x @ w0 + b0).  x:[NN,512] w0:[512,256].
// 4 rows / block, 64 threads per row, 4 consecutive cols per thread.
// ---------------------------------------------------------------------------
__global__ __launch_bounds__(256) void gemm_x_w0(const float* __restrict__ x,
                                                 const float* __restrict__ w0,
                                                 const float* __restrict__ b0,
                                                 float* __restrict__ h0) {
    __shared__ float4 xs[4 * NFEAT / 4];  // 512 float4 = 8 KB
    int r0 = blockIdx.x * 4;
    const float4* xv = (const float4*)(x + (size_t)r0 * NFEAT);
    xs[threadIdx.x]       = xv[threadIdx.x];
    xs[threadIdx.x + 256] = xv[threadIdx.x + 256];
    __syncthreads();
    int row = threadIdx.x >> 6;   // 0..3 (one wave per row -> LDS broadcast)
    int cq  = threadIdx.x & 63;   // float4 column 0..63
    const float* xr = (const float*)(xs + row * (NFEAT / 4));
    const float4* wv = (const float4*)w0;  // [512][64] float4
    float4 acc = ((const float4*)b0)[cq];
    #pragma unroll 8
    for (int k = 0; k < NFEAT; ++k) {
        float a = xr[k];
        float4 w = wv[k * 64 + cq];
        acc.x = fmaf(a, w.x, acc.x);
        acc.y = fmaf(a, w.y, acc.y);
        acc.z = fmaf(a, w.z, acc.z);
        acc.w = fmaf(a, w.w, acc.w);
    }
    acc.x = fmaxf(acc.x, 0.0f);
    acc.y = fmaxf(acc.y, 0.0f);
    acc.z = fmaxf(acc.z, 0.0f);
    acc.w = fmaxf(acc.w, 0.0f);
    ((float4*)(h0 + (size_t)(r0 + row) * NHID))[cq] = acc;
}

// ---------------------------------------------------------------------------
// support = 0.9 * (dinv_i * (dinv_i*h[i] + sum_j dinv_j*h[j])) + 0.1 * h0[i]
// One block (256 threads = 256 feature cols) per row.
// ---------------------------------------------------------------------------
__global__ __launch_bounds__(256) void spmm_support(const float* __restrict__ h,
                                                    const float* __restrict__ h0,
                                                    const float* __restrict__ dinv,
                                                    const int* __restrict__ cnt,
                                                    const int* __restrict__ ell,
                                                    float* __restrict__ sup) {
    int i = blockIdx.x;
    int c = threadIdx.x;
    __shared__ int   sj[MAXDEG];
    __shared__ float sc[MAXDEG];
    int deg = cnt[i];
    float di = dinv[i];
    if (c < deg) {
        int j = ell[(size_t)i * MAXDEG + c];
        sj[c] = j;
        sc[c] = dinv[j];
    }
    __syncthreads();
    float acc = di * h[(size_t)i * NHID + c];  // self loop of A_hat
    for (int e = 0; e < deg; ++e) {
        acc = fmaf(sc[e], h[(size_t)sj[e] * NHID + c], acc);
    }
    float v = 0.9f * (di * acc) + 0.1f * h0[(size_t)i * NHID + c];
    sup[(size_t)i * NHID + c] = v;
}

// ---------------------------------------------------------------------------
// h_new = relu(theta * (s @ w) + (1-theta) * s).  s:[NN,256] w:[256,256].
// ---------------------------------------------------------------------------
__global__ __launch_bounds__(256) void gemm_layer(const float* __restrict__ s,
                                                  const float* __restrict__ w,
                                                  float theta,
                                                  float* __restrict__ hn) {
    __shared__ float4 ss[4 * NHID / 4];  // 256 float4 = 4 KB
    int r0 = blockIdx.x * 4;
    const float4* sv = (const float4*)(s + (size_t)r0 * NHID);
    ss[threadIdx.x] = sv[threadIdx.x];
    __syncthreads();
    int row = threadIdx.x >> 6;
    int cq  = threadIdx.x & 63;
    const float* sr = (const float*)(ss + row * (NHID / 4));
    const float4* wv = (const float4*)w;  // [256][64] float4
    float4 acc = {0.0f, 0.0f, 0.0f, 0.0f};
    #pragma unroll 8
    for (int k = 0; k < NHID; ++k) {
        float a = sr[k];
        float4 wk = wv[k * 64 + cq];
        acc.x = fmaf(a, wk.x, acc.x);
        acc.y = fmaf(a, wk.y, acc.y);
        acc.z = fmaf(a, wk.z, acc.z);
        acc.w = fmaf(a, wk.w, acc.w);
    }
    float om = 1.0f - theta;
    float4 s4 = ((const float4*)sr)[cq];
    float4 o;
    o.x = fmaxf(fmaf(theta, acc.x, om * s4.x), 0.0f);
    o.y = fmaxf(fmaf(theta, acc.y, om * s4.y), 0.0f);
    o.z = fmaxf(fmaf(theta, acc.z, om * s4.z), 0.0f);
    o.w = fmaxf(fmaf(theta, acc.w, om * s4.w), 0.0f);
    ((float4*)(hn + (size_t)(r0 + row) * NHID))[cq] = o;
}

// ---------------------------------------------------------------------------
// logits = h @ w1 + b1; out = log_softmax(logits).  One wave per row.
// ---------------------------------------------------------------------------
__global__ __launch_bounds__(256) void final_logits(const float* __restrict__ h,
                                                    const float* __restrict__ w1,
                                                    const float* __restrict__ b1,
                                                    float* __restrict__ out) {
    __shared__ float hs[4 * NHID];
    int r0 = blockIdx.x * 4;
    ((float4*)hs)[threadIdx.x] = ((const float4*)(h + (size_t)r0 * NHID))[threadIdx.x];
    __syncthreads();
    int row  = threadIdx.x >> 6;
    int lane = threadIdx.x & 63;
    const float* hr = hs + row * NHID;
    float logit = -1e30f;
    if (lane < NCLASS) {
        float acc = b1[lane];
        #pragma unroll 8
        for (int k = 0; k < NHID; ++k)
            acc = fmaf(hr[k], w1[k * NCLASS + lane], acc);
        logit = acc;
    }
    float m = logit;
    #pragma unroll
    for (int off = 32; off > 0; off >>= 1)
        m = fmaxf(m, __shfl_xor(m, off, 64));
    float e = (lane < NCLASS) ? expf(logit - m) : 0.0f;
    float ssum = e;
    #pragma unroll
    for (int off = 32; off > 0; off >>= 1)
        ssum += __shfl_xor(ssum, off, 64);
    float lse = m + logf(ssum);
    if (lane < NCLASS)
        out[(size_t)(r0 + row) * NCLASS + lane] = logit - lse;
}

// ---------------------------------------------------------------------------
extern "C" void kernel_launch(void* const* d_in, const int* in_sizes, int n_in,
                              void* d_out, int out_size, void* d_ws, size_t ws_size,
                              hipStream_t stream) {
    const float* x      = (const float*)d_in[0];
    const float* adj    = (const float*)d_in[1];
    const float* w0     = (const float*)d_in[2];
    const float* b0     = (const float*)d_in[3];
    const float* conv_w = (const float*)d_in[4];
    const float* w1     = (const float*)d_in[5];
    const float* b1     = (const float*)d_in[6];
    float* out = (float*)d_out;

    char* ws = (char*)d_ws;
    size_t off = 0;
    auto alloc = [&](size_t bytes) -> void* {
        void* p = ws + off;
        off = (off + bytes + 255) & ~(size_t)255;
        return p;
    };
    float* dinv = (float*)alloc((size_t)NN * 4);
    int*   cnt  = (int*)  alloc((size_t)NN * 4);
    int*   ell  = (int*)  alloc((size_t)NN * MAXDEG * 4);
    float* h0   = (float*)alloc((size_t)NN * NHID * 4);
    float* hA   = (float*)alloc((size_t)NN * NHID * 4);
    float* hB   = (float*)alloc((size_t)NN * NHID * 4);

    build_graph<<<NN, 256, 0, stream>>>(adj, cnt, ell, dinv);
    gemm_x_w0<<<NN / 4, 256, 0, stream>>>(x, w0, b0, h0);

    const float* hcur = h0;
    for (int l = 0; l < NLAYERS; ++l) {
        float theta = logf(0.5f / (float)(l + 1) + 1.0f);
        spmm_support<<<NN, 256, 0, stream>>>(hcur, h0, dinv, cnt, ell, hB);
        gemm_layer<<<NN / 4, 256, 0, stream>>>(hB, conv_w + (size_t)l * NHID * NHID, theta, hA);
        hcur = hA;
    }
    final_logits<<<NN / 4, 256, 0, stream>>>(hA, w1, b1, out);
}

// Round 2
// 1150.658 us; speedup vs baseline: 1.4359x; 1.4359x over previous
//
#include <hip/hip_runtime.h>
#include <math.h>

#define NN 10000
#define NFEAT 512
#define NHID 256
#define NCLASS 40
#define NLAYERS 8
#define MAXDEG 96

// ---------------------------------------------------------------------------
// build_graph: one block per row; one pass over the 400MB dense adjacency.
// ---------------------------------------------------------------------------
__global__ __launch_bounds__(256) void build_graph(const float* __restrict__ adj,
                                                   int* __restrict__ cnt,
                                                   int* __restrict__ ell,
                                                   float* __restrict__ dinv) {
    int i = blockIdx.x;
    __shared__ int scnt;
    if (threadIdx.x == 0) scnt = 0;
    __syncthreads();
    const float4* row = (const float4*)(adj + (size_t)i * NN);
    const int nv = NN / 4;  // 2500
    int* erow = ell + (size_t)i * MAXDEG;
    for (int f = threadIdx.x; f < nv; f += 256) {
        float4 v = row[f];
        if (v.x != 0.0f) { int s = atomicAdd(&scnt, 1); if (s < MAXDEG) erow[s] = 4*f + 0; }
        if (v.y != 0.0f) { int s = atomicAdd(&scnt, 1); if (s < MAXDEG) erow[s] = 4*f + 1; }
        if (v.z != 0.0f) { int s = atomicAdd(&scnt, 1); if (s < MAXDEG) erow[s] = 4*f + 2; }
        if (v.w != 0.0f) { int s = atomicAdd(&scnt, 1); if (s < MAXDEG) erow[s] = 4*f + 3; }
    }
    __syncthreads();
    if (threadIdx.x == 0) {
        int c = scnt;
        cnt[i] = (c < MAXDEG) ? c : MAXDEG;
        dinv[i] = rsqrtf(1.0f + (float)c);
    }
}

// ---------------------------------------------------------------------------
// Tiled fp32 GEMM: out[N,256] from S[N,K] @ W[K,256].
//   FIRST=true : out = relu(S@W + bias)                      (K=512, x@w0)
//   FIRST=false: out = relu(theta*(S@W) + (1-theta)*S)       (K=256, layer)
// Block: 20 rows x 256 cols; 256 thr; thread = 5 rows x 4 cols (float4).
// S rows in LDS (padded stride K+4 keeps 16B alignment, breaks bank stride);
// W staged in LDS k-tiles of 32 rows.
// ---------------------------------------------------------------------------
template<int K, bool FIRST>
__global__ __launch_bounds__(256, 2) void gemm_tiled(const float* __restrict__ S,
                                                     const float* __restrict__ W,
                                                     const float* __restrict__ bias,
                                                     float theta,
                                                     float* __restrict__ out) {
    constexpr int ROWS = 20;
    constexpr int RPT  = 5;            // rows per thread
    constexpr int RS   = K + 4;        // padded LDS row stride (floats)
    constexpr int C4   = K / 4;        // float4 per input row
    __shared__ float  sM[ROWS * RS];
    __shared__ float4 wt[32 * 64];     // 32 k-rows x 256 cols = 32 KB

    int t  = threadIdx.x;
    int r0 = blockIdx.x * ROWS;
    int cq = t & 63;                   // output float4 column
    int rg = t >> 6;                   // row group 0..3 -> rows rg*5..rg*5+4

    // stage S rows (coalesced b128 global reads, conflict-free LDS writes)
    {
        const float4* Sv = (const float4*)(S + (size_t)r0 * K);
        float4* sM4 = (float4*)sM;
        for (int i = t; i < ROWS * C4; i += 256) {
            int r = i / C4, c = i % C4;
            sM4[r * (RS / 4) + c] = Sv[(size_t)r * C4 + c];
        }
    }

    float4 acc[RPT];
    if (FIRST) {
        float4 b4 = ((const float4*)bias)[cq];
        #pragma unroll
        for (int d = 0; d < RPT; ++d) acc[d] = b4;
    } else {
        #pragma unroll
        for (int d = 0; d < RPT; ++d) acc[d] = make_float4(0.f, 0.f, 0.f, 0.f);
    }

    const float4* Wv = (const float4*)W;  // [K][64] float4
    const float* srow = sM + rg * RPT * RS;

    for (int kt = 0; kt < K / 32; ++kt) {
        __syncthreads();  // waves done reading previous wt (also covers sM stage)
        for (int i = t; i < 2048; i += 256)
            wt[i] = Wv[(size_t)(kt * 32 + (i >> 6)) * 64 + (i & 63)];
        __syncthreads();
        #pragma unroll 8
        for (int kk = 0; kk < 32; ++kk) {
            float4 w4 = wt[kk * 64 + cq];
            int k = kt * 32 + kk;
            #pragma unroll
            for (int d = 0; d < RPT; ++d) {
                float a = srow[d * RS + k];           // LDS broadcast within wave
                acc[d].x = fmaf(a, w4.x, acc[d].x);
                acc[d].y = fmaf(a, w4.y, acc[d].y);
                acc[d].z = fmaf(a, w4.z, acc[d].z);
                acc[d].w = fmaf(a, w4.w, acc[d].w);
            }
        }
    }

    float om = 1.0f - theta;
    #pragma unroll
    for (int d = 0; d < RPT; ++d) {
        int row = r0 + rg * RPT + d;
        float4 o;
        if (FIRST) {
            o.x = fmaxf(acc[d].x, 0.f);
            o.y = fmaxf(acc[d].y, 0.f);
            o.z = fmaxf(acc[d].z, 0.f);
            o.w = fmaxf(acc[d].w, 0.f);
        } else {
            const float4* sM4 = (const float4*)sM;
            float4 s4 = sM4[(rg * RPT + d) * (RS / 4) + cq];
            o.x = fmaxf(fmaf(theta, acc[d].x, om * s4.x), 0.f);
            o.y = fmaxf(fmaf(theta, acc[d].y, om * s4.y), 0.f);
            o.z = fmaxf(fmaf(theta, acc[d].z, om * s4.z), 0.f);
            o.w = fmaxf(fmaf(theta, acc[d].w, om * s4.w), 0.f);
        }
        ((float4*)(out + (size_t)row * NHID))[cq] = o;
    }
}

// ---------------------------------------------------------------------------
// spmm: sup[i] = 0.9*(dinv_i*(dinv_i*h[i] + sum_j dinv_j*h[j])) + 0.1*h0[i]
// One wave per row (4 rows/block), float4 per lane.
// ---------------------------------------------------------------------------
__global__ __launch_bounds__(256) void spmm_support(const float* __restrict__ h,
                                                    const float* __restrict__ h0,
                                                    const float* __restrict__ dinv,
                                                    const int* __restrict__ cnt,
                                                    const int* __restrict__ ell,
                                                    float* __restrict__ sup) {
    int wv = threadIdx.x >> 6;
    int l  = threadIdx.x & 63;
    int i  = blockIdx.x * 4 + wv;    // grid=2500 -> i < 10000 always
    __shared__ int   sj[4][MAXDEG];
    __shared__ float sc[4][MAXDEG];
    int deg = cnt[i];
    float di = dinv[i];
    for (int e = l; e < deg; e += 64) {
        int j = ell[(size_t)i * MAXDEG + e];
        sj[wv][e] = j;
        sc[wv][e] = dinv[j];
    }
    __syncthreads();
    const float4* hv = (const float4*)h;
    float4 acc = hv[(size_t)i * 64 + l];
    acc.x *= di; acc.y *= di; acc.z *= di; acc.w *= di;   // self loop of A_hat
    #pragma unroll 4
    for (int e = 0; e < deg; ++e) {
        float s = sc[wv][e];
        float4 x = hv[(size_t)sj[wv][e] * 64 + l];
        acc.x = fmaf(s, x.x, acc.x);
        acc.y = fmaf(s, x.y, acc.y);
        acc.z = fmaf(s, x.z, acc.z);
        acc.w = fmaf(s, x.w, acc.w);
    }
    float4 h0v = ((const float4*)h0)[(size_t)i * 64 + l];
    float4 o;
    o.x = 0.9f * (di * acc.x) + 0.1f * h0v.x;
    o.y = 0.9f * (di * acc.y) + 0.1f * h0v.y;
    o.z = 0.9f * (di * acc.z) + 0.1f * h0v.z;
    o.w = 0.9f * (di * acc.w) + 0.1f * h0v.w;
    ((float4*)sup)[(size_t)i * 64 + l] = o;
}

// ---------------------------------------------------------------------------
// logits = h @ w1 + b1; out = log_softmax(logits).  One wave per row.
// ---------------------------------------------------------------------------
__global__ __launch_bounds__(256) void final_logits(const float* __restrict__ h,
                                                    const float* __restrict__ w1,
                                                    const float* __restrict__ b1,
                                                    float* __restrict__ out) {
    __shared__ float hs[4 * NHID];
    int r0 = blockIdx.x * 4;
    ((float4*)hs)[threadIdx.x] = ((const float4*)(h + (size_t)r0 * NHID))[threadIdx.x];
    __syncthreads();
    int row  = threadIdx.x >> 6;
    int lane = threadIdx.x & 63;
    const float* hr = hs + row * NHID;
    float logit = -1e30f;
    if (lane < NCLASS) {
        float acc = b1[lane];
        #pragma unroll 8
        for (int k = 0; k < NHID; ++k)
            acc = fmaf(hr[k], w1[k * NCLASS + lane], acc);
        logit = acc;
    }
    float m = logit;
    #pragma unroll
    for (int off = 32; off > 0; off >>= 1)
        m = fmaxf(m, __shfl_xor(m, off, 64));
    float e = (lane < NCLASS) ? expf(logit - m) : 0.0f;
    float ssum = e;
    #pragma unroll
    for (int off = 32; off > 0; off >>= 1)
        ssum += __shfl_xor(ssum, off, 64);
    float lse = m + logf(ssum);
    if (lane < NCLASS)
        out[(size_t)(r0 + row) * NCLASS + lane] = logit - lse;
}

// ---------------------------------------------------------------------------
extern "C" void kernel_launch(void* const* d_in, const int* in_sizes, int n_in,
                              void* d_out, int out_size, void* d_ws, size_t ws_size,
                              hipStream_t stream) {
    const float* x      = (const float*)d_in[0];
    const float* adj    = (const float*)d_in[1];
    const float* w0     = (const float*)d_in[2];
    const float* b0     = (const float*)d_in[3];
    const float* conv_w = (const float*)d_in[4];
    const float* w1     = (const float*)d_in[5];
    const float* b1     = (const float*)d_in[6];
    float* out = (float*)d_out;

    char* ws = (char*)d_ws;
    size_t off = 0;
    auto alloc = [&](size_t bytes) -> void* {
        void* p = ws + off;
        off = (off + bytes + 255) & ~(size_t)255;
        return p;
    };
    float* dinv = (float*)alloc((size_t)NN * 4);
    int*   cnt  = (int*)  alloc((size_t)NN * 4);
    int*   ell  = (int*)  alloc((size_t)NN * MAXDEG * 4);
    float* h0   = (float*)alloc((size_t)NN * NHID * 4);
    float* hA   = (float*)alloc((size_t)NN * NHID * 4);
    float* hB   = (float*)alloc((size_t)NN * NHID * 4);

    build_graph<<<NN, 256, 0, stream>>>(adj, cnt, ell, dinv);
    gemm_tiled<NFEAT, true><<<NN / 20, 256, 0, stream>>>(x, w0, b0, 0.0f, h0);

    const float* hcur = h0;
    for (int l = 0; l < NLAYERS; ++l) {
        float theta = logf(0.5f / (float)(l + 1) + 1.0f);
        spmm_support<<<NN / 4, 256, 0, stream>>>(hcur, h0, dinv, cnt, ell, hB);
        gemm_tiled<NHID, false><<<NN / 20, 256, 0, stream>>>(
            hB, conv_w + (size_t)l * NHID * NHID, nullptr, theta, hA);
        hcur = hA;
    }
    final_logits<<<NN / 4, 256, 0, stream>>>(hA, w1, b1, out);
}

// Round 3
// 1101.353 us; speedup vs baseline: 1.5002x; 1.0448x over previous
//
#include <hip/hip_runtime.h>
#include <math.h>

#define NN 10000
#define NFEAT 512
#define NHID 256
#define NCLASS 40
#define NLAYERS 8
#define MAXDEG 96

typedef __attribute__((ext_vector_type(8))) short bf16x8;
typedef __attribute__((ext_vector_type(4))) float floatx4;
typedef __attribute__((ext_vector_type(4))) unsigned short ushort4v;

__device__ __forceinline__ unsigned short f2bf(float f) {
    union { float f; unsigned int u; } v; v.f = f;
    unsigned int r = v.u + 0x7fffu + ((v.u >> 16) & 1u);  // RNE
    return (unsigned short)(r >> 16);
}
__device__ __forceinline__ float bf2f(unsigned short h) {
    union { unsigned int u; float f; } v; v.u = ((unsigned int)h) << 16;
    return v.f;
}

// ---------------------------------------------------------------------------
// build_graph: one block per row; one pass over the 400MB dense adjacency.
// ---------------------------------------------------------------------------
__global__ __launch_bounds__(256) void build_graph(const float* __restrict__ adj,
                                                   int* __restrict__ cnt,
                                                   int* __restrict__ ell,
                                                   float* __restrict__ dinv) {
    int i = blockIdx.x;
    __shared__ int scnt;
    if (threadIdx.x == 0) scnt = 0;
    __syncthreads();
    const float4* row = (const float4*)(adj + (size_t)i * NN);
    const int nv = NN / 4;  // 2500
    int* erow = ell + (size_t)i * MAXDEG;
    for (int f = threadIdx.x; f < nv; f += 256) {
        float4 v = row[f];
        if (v.x != 0.0f) { int s = atomicAdd(&scnt, 1); if (s < MAXDEG) erow[s] = 4*f + 0; }
        if (v.y != 0.0f) { int s = atomicAdd(&scnt, 1); if (s < MAXDEG) erow[s] = 4*f + 1; }
        if (v.z != 0.0f) { int s = atomicAdd(&scnt, 1); if (s < MAXDEG) erow[s] = 4*f + 2; }
        if (v.w != 0.0f) { int s = atomicAdd(&scnt, 1); if (s < MAXDEG) erow[s] = 4*f + 3; }
    }
    __syncthreads();
    if (threadIdx.x == 0) {
        int c = scnt;
        cnt[i] = (c < MAXDEG) ? c : MAXDEG;
        dinv[i] = rsqrtf(1.0f + (float)c);
    }
}

// ---------------------------------------------------------------------------
// convert x -> bf16 (4 elements / thread)
// ---------------------------------------------------------------------------
__global__ __launch_bounds__(256) void convert_x(const float* __restrict__ x,
                                                 unsigned short* __restrict__ xb) {
    int idx = blockIdx.x * 256 + threadIdx.x;   // float4 index; total 1,280,000
    float4 v = ((const float4*)x)[idx];
    ushort4v o;
    o.x = f2bf(v.x); o.y = f2bf(v.y); o.z = f2bf(v.z); o.w = f2bf(v.w);
    ((ushort4v*)xb)[idx] = o;
}

// ---------------------------------------------------------------------------
// prep_weights: transpose-convert w0 [512][256] -> w0t bf16 [256 n][512 k]
// and conv_w 8x[256][256] -> cwt bf16 8x[256 n][256 k].
// ---------------------------------------------------------------------------
__global__ __launch_bounds__(256) void prep_weights(const float* __restrict__ w0,
                                                    const float* __restrict__ cw,
                                                    unsigned short* __restrict__ w0t,
                                                    unsigned short* __restrict__ cwt) {
    int idx = blockIdx.x * 256 + threadIdx.x;   // total 131072 + 524288 = 655360
    if (idx < 131072) {
        int n = idx >> 9, k = idx & 511;
        w0t[idx] = f2bf(w0[(size_t)k * 256 + n]);
    } else {
        int j = idx - 131072;
        int l = j >> 16;
        int r = j & 65535;
        int n = r >> 8, k = r & 255;
        cwt[j] = f2bf(cw[(size_t)l * 65536 + (size_t)k * 256 + n]);
    }
}

// ---------------------------------------------------------------------------
// MFMA bf16 GEMM: out[N,256] = f(S[N,K] @ W[K,256]) with W given transposed
// as Wt[256 n][K k] bf16.  One wave per 16-row stripe (625 waves).
//   FIRST=true : out = relu(S@W + bias)
//   FIRST=false: out = relu(theta*(S@W) + (1-theta)*res)
// A frag (16x16x32): lane holds A[m=lane&15][k=quad*8+j]; B frag from Wt:
// lane holds B[k=quad*8+j][n=lane&15] = Wt[lane&15][quad*8+j] (16B contig).
// C/D: col n = lane&15, row m = quad*4+reg.
// Writes fp32 output (residual/final use) and bf16 copy (next gather/GEMM).
// ---------------------------------------------------------------------------
template<int K, bool FIRST>
__global__ __launch_bounds__(256) void gemm_mfma(const unsigned short* __restrict__ Ab,
                                                 const unsigned short* __restrict__ Wt,
                                                 const float* __restrict__ res,
                                                 float theta,
                                                 float* __restrict__ hf,
                                                 unsigned short* __restrict__ hb) {
    int wave = (blockIdx.x * 256 + threadIdx.x) >> 6;
    if (wave >= NN / 16) return;               // wave-uniform exit
    int lane = threadIdx.x & 63;
    int lrow = lane & 15;
    int quad = lane >> 4;
    int r0 = wave * 16;

    constexpr int NF = K / 32;
    bf16x8 a[NF];
    const unsigned short* arow = Ab + (size_t)(r0 + lrow) * K + quad * 8;
    #pragma unroll
    for (int f = 0; f < NF; ++f)
        a[f] = *(const bf16x8*)(arow + f * 32);

    float om = 1.0f - theta;
    for (int nt = 0; nt < 16; ++nt) {
        floatx4 acc = {0.f, 0.f, 0.f, 0.f};
        const unsigned short* wrow = Wt + (size_t)(nt * 16 + lrow) * K + quad * 8;
        #pragma unroll
        for (int f = 0; f < NF; ++f) {
            bf16x8 b = *(const bf16x8*)(wrow + f * 32);
            acc = __builtin_amdgcn_mfma_f32_16x16x32_bf16(a[f], b, acc, 0, 0, 0);
        }
        int col = nt * 16 + lrow;
        #pragma unroll
        for (int r = 0; r < 4; ++r) {
            int row = r0 + quad * 4 + r;
            float o;
            if (FIRST) {
                o = fmaxf(acc[r] + res[col], 0.f);
            } else {
                float s = res[(size_t)row * NHID + col];
                o = fmaxf(fmaf(theta, acc[r], om * s), 0.f);
            }
            hf[(size_t)row * NHID + col] = o;
            hb[(size_t)row * NHID + col] = f2bf(o);
        }
    }
}

// ---------------------------------------------------------------------------
// spmm: sup[i] = 0.9*(dinv_i*(dinv_i*h[i] + sum_j dinv_j*h[j])) + 0.1*h0[i]
// One wave per row (4 rows/block); neighbor rows gathered as bf16 (8B/lane),
// self row + h0 in fp32. Writes fp32 sup (residual) + bf16 sup (GEMM A).
// ---------------------------------------------------------------------------
__global__ __launch_bounds__(256) void spmm_support(const float* __restrict__ hf,
                                                    const unsigned short* __restrict__ hb,
                                                    const float* __restrict__ h0,
                                                    const float* __restrict__ dinv,
                                                    const int* __restrict__ cnt,
                                                    const int* __restrict__ ell,
                                                    float* __restrict__ sup,
                                                    unsigned short* __restrict__ supb) {
    int wv = threadIdx.x >> 6;
    int l  = threadIdx.x & 63;
    int i  = blockIdx.x * 4 + wv;    // grid=2500 -> i < 10000 always
    __shared__ int   sj[4][MAXDEG];
    __shared__ float sc[4][MAXDEG];
    int deg = cnt[i];
    float di = dinv[i];
    for (int e = l; e < deg; e += 64) {
        int j = ell[(size_t)i * MAXDEG + e];
        sj[wv][e] = j;
        sc[wv][e] = dinv[j];
    }
    __syncthreads();
    float4 acc = ((const float4*)hf)[(size_t)i * 64 + l];
    acc.x *= di; acc.y *= di; acc.z *= di; acc.w *= di;   // self loop of A_hat
    const ushort4v* hv = (const ushort4v*)hb;
    #pragma unroll 4
    for (int e = 0; e < deg; ++e) {
        float s = sc[wv][e];
        ushort4v xb = hv[(size_t)sj[wv][e] * 64 + l];
        acc.x = fmaf(s, bf2f(xb.x), acc.x);
        acc.y = fmaf(s, bf2f(xb.y), acc.y);
        acc.z = fmaf(s, bf2f(xb.z), acc.z);
        acc.w = fmaf(s, bf2f(xb.w), acc.w);
    }
    float4 h0v = ((const float4*)h0)[(size_t)i * 64 + l];
    float4 o;
    o.x = 0.9f * (di * acc.x) + 0.1f * h0v.x;
    o.y = 0.9f * (di * acc.y) + 0.1f * h0v.y;
    o.z = 0.9f * (di * acc.z) + 0.1f * h0v.z;
    o.w = 0.9f * (di * acc.w) + 0.1f * h0v.w;
    ((float4*)sup)[(size_t)i * 64 + l] = o;
    ushort4v ob;
    ob.x = f2bf(o.x); ob.y = f2bf(o.y); ob.z = f2bf(o.z); ob.w = f2bf(o.w);
    ((ushort4v*)supb)[(size_t)i * 64 + l] = ob;
}

// ---------------------------------------------------------------------------
// logits = h @ w1 + b1; out = log_softmax(logits).  One wave per row.
// ---------------------------------------------------------------------------
__global__ __launch_bounds__(256) void final_logits(const float* __restrict__ h,
                                                    const float* __restrict__ w1,
                                                    const float* __restrict__ b1,
                                                    float* __restrict__ out) {
    __shared__ float hs[4 * NHID];
    int r0 = blockIdx.x * 4;
    ((float4*)hs)[threadIdx.x] = ((const float4*)(h + (size_t)r0 * NHID))[threadIdx.x];
    __syncthreads();
    int row  = threadIdx.x >> 6;
    int lane = threadIdx.x & 63;
    const float* hr = hs + row * NHID;
    float logit = -1e30f;
    if (lane < NCLASS) {
        float acc = b1[lane];
        #pragma unroll 8
        for (int k = 0; k < NHID; ++k)
            acc = fmaf(hr[k], w1[k * NCLASS + lane], acc);
        logit = acc;
    }
    float m = logit;
    #pragma unroll
    for (int off = 32; off > 0; off >>= 1)
        m = fmaxf(m, __shfl_xor(m, off, 64));
    float e = (lane < NCLASS) ? expf(logit - m) : 0.0f;
    float ssum = e;
    #pragma unroll
    for (int off = 32; off > 0; off >>= 1)
        ssum += __shfl_xor(ssum, off, 64);
    float lse = m + logf(ssum);
    if (lane < NCLASS)
        out[(size_t)(r0 + row) * NCLASS + lane] = logit - lse;
}

// ---------------------------------------------------------------------------
extern "C" void kernel_launch(void* const* d_in, const int* in_sizes, int n_in,
                              void* d_out, int out_size, void* d_ws, size_t ws_size,
                              hipStream_t stream) {
    const float* x      = (const float*)d_in[0];
    const float* adj    = (const float*)d_in[1];
    const float* w0     = (const float*)d_in[2];
    const float* b0     = (const float*)d_in[3];
    const float* conv_w = (const float*)d_in[4];
    const float* w1     = (const float*)d_in[5];
    const float* b1     = (const float*)d_in[6];
    float* out = (float*)d_out;

    char* ws = (char*)d_ws;
    size_t off = 0;
    auto alloc = [&](size_t bytes) -> void* {
        void* p = ws + off;
        off = (off + bytes + 255) & ~(size_t)255;
        return p;
    };
    float*          dinv = (float*)alloc((size_t)NN * 4);
    int*            cnt  = (int*)  alloc((size_t)NN * 4);
    int*            ell  = (int*)  alloc((size_t)NN * MAXDEG * 4);
    unsigned short* xb   = (unsigned short*)alloc((size_t)NN * NFEAT * 2);
    unsigned short* w0t  = (unsigned short*)alloc((size_t)NFEAT * NHID * 2);
    unsigned short* cwt  = (unsigned short*)alloc((size_t)NLAYERS * NHID * NHID * 2);
    float*          h0f  = (float*)alloc((size_t)NN * NHID * 4);
    unsigned short* h0b  = (unsigned short*)alloc((size_t)NN * NHID * 2);
    float*          hAf  = (float*)alloc((size_t)NN * NHID * 4);
    unsigned short* hAb  = (unsigned short*)alloc((size_t)NN * NHID * 2);
    float*          supf = (float*)alloc((size_t)NN * NHID * 4);
    unsigned short* supb = (unsigned short*)alloc((size_t)NN * NHID * 2);

    build_graph<<<NN, 256, 0, stream>>>(adj, cnt, ell, dinv);
    convert_x<<<(NN * NFEAT / 4) / 256, 256, 0, stream>>>(x, xb);
    prep_weights<<<(131072 + NLAYERS * NHID * NHID) / 256, 256, 0, stream>>>(w0, conv_w, w0t, cwt);

    // h0 = relu(x @ w0 + b0)
    gemm_mfma<NFEAT, true><<<(NN / 16 + 3) / 4, 256, 0, stream>>>(xb, w0t, b0, 0.0f, h0f, h0b);

    const float* hcf = h0f;
    const unsigned short* hcb = h0b;
    for (int l = 0; l < NLAYERS; ++l) {
        float theta = logf(0.5f / (float)(l + 1) + 1.0f);
        spmm_support<<<NN / 4, 256, 0, stream>>>(hcf, hcb, h0f, dinv, cnt, ell, supf, supb);
        gemm_mfma<NHID, false><<<(NN / 16 + 3) / 4, 256, 0, stream>>>(
            supb, cwt + (size_t)l * NHID * NHID, supf, theta, hAf, hAb);
        hcf = hAf; hcb = hAb;
    }
    final_logits<<<NN / 4, 256, 0, stream>>>(hAf, w1, b1, out);
}

// Round 4
// 886.068 us; speedup vs baseline: 1.8647x; 1.2430x over previous
//
#include <hip/hip_runtime.h>
#include <math.h>

#define NN 10000
#define NFEAT 512
#define NHID 256
#define NCLASS 40
#define NLAYERS 8
#define MAXDEG 96

typedef __attribute__((ext_vector_type(8))) short bf16x8;
typedef __attribute__((ext_vector_type(4))) float floatx4;
typedef __attribute__((ext_vector_type(4))) unsigned short ushort4v;

__device__ __forceinline__ unsigned short f2bf(float f) {
    union { float f; unsigned int u; } v; v.f = f;
    unsigned int r = v.u + 0x7fffu + ((v.u >> 16) & 1u);  // RNE
    return (unsigned short)(r >> 16);
}
__device__ __forceinline__ float bf2f(unsigned short h) {
    union { unsigned int u; float f; } v; v.u = ((unsigned int)h) << 16;
    return v.f;
}

// ---------------------------------------------------------------------------
// build_graph: one block per row; one pass over the 400MB dense adjacency.
// ---------------------------------------------------------------------------
__global__ __launch_bounds__(256) void build_graph(const float* __restrict__ adj,
                                                   int* __restrict__ cnt,
                                                   int* __restrict__ ell,
                                                   float* __restrict__ dinv) {
    int i = blockIdx.x;
    __shared__ int scnt;
    if (threadIdx.x == 0) scnt = 0;
    __syncthreads();
    const float4* row = (const float4*)(adj + (size_t)i * NN);
    const int nv = NN / 4;  // 2500
    int* erow = ell + (size_t)i * MAXDEG;
    for (int f = threadIdx.x; f < nv; f += 256) {
        float4 v = row[f];
        if (v.x != 0.0f) { int s = atomicAdd(&scnt, 1); if (s < MAXDEG) erow[s] = 4*f + 0; }
        if (v.y != 0.0f) { int s = atomicAdd(&scnt, 1); if (s < MAXDEG) erow[s] = 4*f + 1; }
        if (v.z != 0.0f) { int s = atomicAdd(&scnt, 1); if (s < MAXDEG) erow[s] = 4*f + 2; }
        if (v.w != 0.0f) { int s = atomicAdd(&scnt, 1); if (s < MAXDEG) erow[s] = 4*f + 3; }
    }
    __syncthreads();
    if (threadIdx.x == 0) {
        int c = scnt;
        cnt[i] = (c < MAXDEG) ? c : MAXDEG;
        dinv[i] = rsqrtf(1.0f + (float)c);
    }
}

// ---------------------------------------------------------------------------
// convert x -> bf16 (4 elements / thread)
// ---------------------------------------------------------------------------
__global__ __launch_bounds__(256) void convert_x(const float* __restrict__ x,
                                                 unsigned short* __restrict__ xb) {
    int idx = blockIdx.x * 256 + threadIdx.x;
    float4 v = ((const float4*)x)[idx];
    ushort4v o;
    o.x = f2bf(v.x); o.y = f2bf(v.y); o.z = f2bf(v.z); o.w = f2bf(v.w);
    ((ushort4v*)xb)[idx] = o;
}

// ---------------------------------------------------------------------------
// prep_weights: transpose-convert w0 [512][256] -> w0t bf16 [256 n][512 k]
// and conv_w 8x[256][256] -> cwt bf16 8x[256 n][256 k].
// ---------------------------------------------------------------------------
__global__ __launch_bounds__(256) void prep_weights(const float* __restrict__ w0,
                                                    const float* __restrict__ cw,
                                                    unsigned short* __restrict__ w0t,
                                                    unsigned short* __restrict__ cwt) {
    int idx = blockIdx.x * 256 + threadIdx.x;
    if (idx < 131072) {
        int n = idx >> 9, k = idx & 511;
        w0t[idx] = f2bf(w0[(size_t)k * 256 + n]);
    } else {
        int j = idx - 131072;
        int l = j >> 16;
        int r = j & 65535;
        int n = r >> 8, k = r & 255;
        cwt[j] = f2bf(cw[(size_t)l * 65536 + (size_t)k * 256 + n]);
    }
}

// ---------------------------------------------------------------------------
// gemm0: h0 = relu(x @ w0 + b0).  625 blocks x 4 waves; block = 16 rows;
// wave = 4 col-tiles of 16 (16x16x32 MFMA, K=512 -> 16 frags).
// ---------------------------------------------------------------------------
__global__ __launch_bounds__(256) void gemm0_mfma(const unsigned short* __restrict__ xb,
                                                  const unsigned short* __restrict__ w0t,
                                                  const float* __restrict__ b0,
                                                  float* __restrict__ h0f,
                                                  unsigned short* __restrict__ h0b) {
    int t = threadIdx.x, wv = t >> 6, lane = t & 63;
    int lrow = lane & 15, quad = lane >> 4;
    int r0 = blockIdx.x * 16;

    bf16x8 a[16];
    const unsigned short* arow = xb + (size_t)(r0 + lrow) * NFEAT + quad * 8;
    #pragma unroll
    for (int f = 0; f < 16; ++f)
        a[f] = *(const bf16x8*)(arow + f * 32);

    #pragma unroll 1
    for (int n = 0; n < 4; ++n) {
        int nt = wv * 4 + n;
        floatx4 acc = {0.f, 0.f, 0.f, 0.f};
        const unsigned short* wrow = w0t + (size_t)(nt * 16 + lrow) * NFEAT + quad * 8;
        #pragma unroll
        for (int f = 0; f < 16; ++f) {
            bf16x8 b = *(const bf16x8*)(wrow + f * 32);
            acc = __builtin_amdgcn_mfma_f32_16x16x32_bf16(a[f], b, acc, 0, 0, 0);
        }
        int col = nt * 16 + lrow;
        float bias = b0[col];
        #pragma unroll
        for (int r = 0; r < 4; ++r) {
            int row = r0 + quad * 4 + r;
            float o = fmaxf(acc[r] + bias, 0.f);
            h0f[(size_t)row * NHID + col] = o;
            h0b[(size_t)row * NHID + col] = f2bf(o);
        }
    }
}

// ---------------------------------------------------------------------------
// layer_fused: per layer, block = 16 rows (grid 625), 4 waves.
// Phase 1 (spmm): wave wv computes sup for rows wv*4..wv*4+3 into LDS:
//   sup[i] = 0.9*(dinv_i*(dinv_i*h[i] + sum_j dinv_j*h[j])) + 0.1*h0[i]
//   (h gathered as bf16; h0 fp32). fp32 + bf16 copies, padded stride 264.
// Phase 2 (GEMM): wave wv computes cols wv*64..wv*64+63:
//   out = relu(theta*(sup @ W) + (1-theta)*sup), W as Wt[256 n][256 k] bf16.
// Writes bf16 h (next layer); fp32 h only when LAST (final_logits input).
// ---------------------------------------------------------------------------
template<bool LAST>
__global__ __launch_bounds__(256) void layer_fused(const unsigned short* __restrict__ hb,
                                                   const float* __restrict__ h0f,
                                                   const float* __restrict__ dinv,
                                                   const int* __restrict__ cnt,
                                                   const int* __restrict__ ell,
                                                   const unsigned short* __restrict__ Wt,
                                                   float theta,
                                                   unsigned short* __restrict__ hb_out,
                                                   float* __restrict__ hf_out) {
    __shared__ float          supf[16][264];   // padded: stride 264 floats
    __shared__ unsigned short supb[16][264];   // stride 264 shorts (528B)
    __shared__ int   sj[16][MAXDEG];
    __shared__ float scl[16][MAXDEG];

    int t = threadIdx.x, wv = t >> 6, lane = t & 63;
    int r0 = blockIdx.x * 16;

    // ---- stage neighbor lists for this wave's 4 rows ----
    #pragma unroll
    for (int rr = 0; rr < 4; ++rr) {
        int lr = wv * 4 + rr;
        int i  = r0 + lr;
        int deg = cnt[i];
        for (int e = lane; e < deg; e += 64) {
            int j = ell[(size_t)i * MAXDEG + e];
            sj[lr][e]  = j;
            scl[lr][e] = dinv[j];
        }
    }
    __syncthreads();

    // ---- phase 1: gather + mix, sup -> LDS ----
    const ushort4v* hv = (const ushort4v*)hb;
    #pragma unroll 1
    for (int rr = 0; rr < 4; ++rr) {
        int lr = wv * 4 + rr;
        int i  = r0 + lr;
        int deg = cnt[i];
        float di = dinv[i];
        ushort4v sv = hv[(size_t)i * 64 + lane];
        float4 acc;
        acc.x = di * bf2f(sv.x);
        acc.y = di * bf2f(sv.y);
        acc.z = di * bf2f(sv.z);
        acc.w = di * bf2f(sv.w);
        #pragma unroll 4
        for (int e = 0; e < deg; ++e) {
            float s = scl[lr][e];
            ushort4v xv = hv[(size_t)sj[lr][e] * 64 + lane];
            acc.x = fmaf(s, bf2f(xv.x), acc.x);
            acc.y = fmaf(s, bf2f(xv.y), acc.y);
            acc.z = fmaf(s, bf2f(xv.z), acc.z);
            acc.w = fmaf(s, bf2f(xv.w), acc.w);
        }
        float4 h0v = ((const float4*)h0f)[(size_t)i * 64 + lane];
        float4 o;
        o.x = 0.9f * (di * acc.x) + 0.1f * h0v.x;
        o.y = 0.9f * (di * acc.y) + 0.1f * h0v.y;
        o.z = 0.9f * (di * acc.z) + 0.1f * h0v.z;
        o.w = 0.9f * (di * acc.w) + 0.1f * h0v.w;
        *(float4*)&supf[lr][4 * lane] = o;
        ushort4v ob;
        ob.x = f2bf(o.x); ob.y = f2bf(o.y); ob.z = f2bf(o.z); ob.w = f2bf(o.w);
        *(ushort4v*)&supb[lr][4 * lane] = ob;
    }
    __syncthreads();

    // ---- phase 2: MFMA GEMM on the 16-row tile ----
    int lrow = lane & 15, quad = lane >> 4;
    bf16x8 a[8];
    #pragma unroll
    for (int f = 0; f < 8; ++f)
        a[f] = *(const bf16x8*)&supb[lrow][quad * 8 + f * 32];

    float om = 1.0f - theta;
    #pragma unroll 1
    for (int n = 0; n < 4; ++n) {
        int nt = wv * 4 + n;
        floatx4 acc = {0.f, 0.f, 0.f, 0.f};
        const unsigned short* wrow = Wt + (size_t)(nt * 16 + lrow) * NHID + quad * 8;
        #pragma unroll
        for (int f = 0; f < 8; ++f) {
            bf16x8 b = *(const bf16x8*)(wrow + f * 32);
            acc = __builtin_amdgcn_mfma_f32_16x16x32_bf16(a[f], b, acc, 0, 0, 0);
        }
        int col = nt * 16 + lrow;
        #pragma unroll
        for (int r = 0; r < 4; ++r) {
            int lr2 = quad * 4 + r;
            int row = r0 + lr2;
            float s = supf[lr2][col];
            float o = fmaxf(fmaf(theta, acc[r], om * s), 0.f);
            hb_out[(size_t)row * NHID + col] = f2bf(o);
            if (LAST) hf_out[(size_t)row * NHID + col] = o;
        }
    }
}

// ---------------------------------------------------------------------------
// logits = h @ w1 + b1; out = log_softmax(logits).  One wave per row.
// ---------------------------------------------------------------------------
__global__ __launch_bounds__(256) void final_logits(const float* __restrict__ h,
                                                    const float* __restrict__ w1,
                                                    const float* __restrict__ b1,
                                                    float* __restrict__ out) {
    __shared__ float hs[4 * NHID];
    int r0 = blockIdx.x * 4;
    ((float4*)hs)[threadIdx.x] = ((const float4*)(h + (size_t)r0 * NHID))[threadIdx.x];
    __syncthreads();
    int row  = threadIdx.x >> 6;
    int lane = threadIdx.x & 63;
    const float* hr = hs + row * NHID;
    float logit = -1e30f;
    if (lane < NCLASS) {
        float acc = b1[lane];
        #pragma unroll 8
        for (int k = 0; k < NHID; ++k)
            acc = fmaf(hr[k], w1[k * NCLASS + lane], acc);
        logit = acc;
    }
    float m = logit;
    #pragma unroll
    for (int off = 32; off > 0; off >>= 1)
        m = fmaxf(m, __shfl_xor(m, off, 64));
    float e = (lane < NCLASS) ? expf(logit - m) : 0.0f;
    float ssum = e;
    #pragma unroll
    for (int off = 32; off > 0; off >>= 1)
        ssum += __shfl_xor(ssum, off, 64);
    float lse = m + logf(ssum);
    if (lane < NCLASS)
        out[(size_t)(r0 + row) * NCLASS + lane] = logit - lse;
}

// ---------------------------------------------------------------------------
extern "C" void kernel_launch(void* const* d_in, const int* in_sizes, int n_in,
                              void* d_out, int out_size, void* d_ws, size_t ws_size,
                              hipStream_t stream) {
    const float* x      = (const float*)d_in[0];
    const float* adj    = (const float*)d_in[1];
    const float* w0     = (const float*)d_in[2];
    const float* b0     = (const float*)d_in[3];
    const float* conv_w = (const float*)d_in[4];
    const float* w1     = (const float*)d_in[5];
    const float* b1     = (const float*)d_in[6];
    float* out = (float*)d_out;

    char* ws = (char*)d_ws;
    size_t off = 0;
    auto alloc = [&](size_t bytes) -> void* {
        void* p = ws + off;
        off = (off + bytes + 255) & ~(size_t)255;
        return p;
    };
    float*          dinv = (float*)alloc((size_t)NN * 4);
    int*            cnt  = (int*)  alloc((size_t)NN * 4);
    int*            ell  = (int*)  alloc((size_t)NN * MAXDEG * 4);
    unsigned short* xb   = (unsigned short*)alloc((size_t)NN * NFEAT * 2);
    unsigned short* w0t  = (unsigned short*)alloc((size_t)NFEAT * NHID * 2);
    unsigned short* cwt  = (unsigned short*)alloc((size_t)NLAYERS * NHID * NHID * 2);
    float*          h0f  = (float*)alloc((size_t)NN * NHID * 4);
    unsigned short* h0b  = (unsigned short*)alloc((size_t)NN * NHID * 2);
    unsigned short* hPb  = (unsigned short*)alloc((size_t)NN * NHID * 2);
    unsigned short* hQb  = (unsigned short*)alloc((size_t)NN * NHID * 2);
    float*          hfL  = (float*)alloc((size_t)NN * NHID * 4);

    build_graph<<<NN, 256, 0, stream>>>(adj, cnt, ell, dinv);
    convert_x<<<(NN * NFEAT / 4) / 256, 256, 0, stream>>>(x, xb);
    prep_weights<<<(131072 + NLAYERS * NHID * NHID) / 256, 256, 0, stream>>>(w0, conv_w, w0t, cwt);

    gemm0_mfma<<<NN / 16, 256, 0, stream>>>(xb, w0t, b0, h0f, h0b);

    const unsigned short* hcb = h0b;
    for (int l = 0; l < NLAYERS; ++l) {
        float theta = logf(0.5f / (float)(l + 1) + 1.0f);
        unsigned short* nxt = (l & 1) ? hQb : hPb;
        const unsigned short* wt = cwt + (size_t)l * NHID * NHID;
        if (l == NLAYERS - 1)
            layer_fused<true><<<NN / 16, 256, 0, stream>>>(hcb, h0f, dinv, cnt, ell, wt, theta, nxt, hfL);
        else
            layer_fused<false><<<NN / 16, 256, 0, stream>>>(hcb, h0f, dinv, cnt, ell, wt, theta, nxt, nullptr);
        hcb = nxt;
    }
    final_logits<<<NN / 4, 256, 0, stream>>>(hfL, w1, b1, out);
}

// Round 5
// 880.157 us; speedup vs baseline: 1.8772x; 1.0067x over previous
//
#include <hip/hip_runtime.h>
#include <math.h>

#define NN 10000
#define NFEAT 512
#define NHID 256
#define NCLASS 40
#define NLAYERS 8
#define MAXDEG 96

typedef __attribute__((ext_vector_type(8))) short bf16x8;
typedef __attribute__((ext_vector_type(4))) float floatx4;
typedef __attribute__((ext_vector_type(4))) unsigned short ushort4v;

__device__ __forceinline__ unsigned short f2bf(float f) {
    union { float f; unsigned int u; } v; v.f = f;
    unsigned int r = v.u + 0x7fffu + ((v.u >> 16) & 1u);  // RNE
    return (unsigned short)(r >> 16);
}
__device__ __forceinline__ float bf2f(unsigned short h) {
    union { unsigned int u; float f; } v; v.u = ((unsigned int)h) << 16;
    return v.f;
}

// ---------------------------------------------------------------------------
// build_graph: one block per row; one pass over the 400MB dense adjacency.
// ---------------------------------------------------------------------------
__global__ __launch_bounds__(256) void build_graph(const float* __restrict__ adj,
                                                   int* __restrict__ cnt,
                                                   int* __restrict__ ell,
                                                   float* __restrict__ dinv) {
    int i = blockIdx.x;
    __shared__ int scnt;
    if (threadIdx.x == 0) scnt = 0;
    __syncthreads();
    const float4* row = (const float4*)(adj + (size_t)i * NN);
    const int nv = NN / 4;  // 2500
    int* erow = ell + (size_t)i * MAXDEG;
    for (int f = threadIdx.x; f < nv; f += 256) {
        float4 v = row[f];
        if (v.x != 0.0f) { int s = atomicAdd(&scnt, 1); if (s < MAXDEG) erow[s] = 4*f + 0; }
        if (v.y != 0.0f) { int s = atomicAdd(&scnt, 1); if (s < MAXDEG) erow[s] = 4*f + 1; }
        if (v.z != 0.0f) { int s = atomicAdd(&scnt, 1); if (s < MAXDEG) erow[s] = 4*f + 2; }
        if (v.w != 0.0f) { int s = atomicAdd(&scnt, 1); if (s < MAXDEG) erow[s] = 4*f + 3; }
    }
    __syncthreads();
    if (threadIdx.x == 0) {
        int c = scnt;
        cnt[i] = (c < MAXDEG) ? c : MAXDEG;
        dinv[i] = rsqrtf(1.0f + (float)c);
    }
}

// ---------------------------------------------------------------------------
// convert x -> bf16 (4 elements / thread)
// ---------------------------------------------------------------------------
__global__ __launch_bounds__(256) void convert_x(const float* __restrict__ x,
                                                 unsigned short* __restrict__ xb) {
    int idx = blockIdx.x * 256 + threadIdx.x;
    float4 v = ((const float4*)x)[idx];
    ushort4v o;
    o.x = f2bf(v.x); o.y = f2bf(v.y); o.z = f2bf(v.z); o.w = f2bf(v.w);
    ((ushort4v*)xb)[idx] = o;
}

// ---------------------------------------------------------------------------
// prep_weights:
//   w0t[n][k]  = bf16(w0[k][n])                                 (256x512)
//   Mt[l][n][k] = bf16(theta_l * cw[l][k][n] + (1-theta_l)*I)   (fold residual!)
// theta_l = log(0.5/(l+1) + 1)
// ---------------------------------------------------------------------------
__global__ __launch_bounds__(256) void prep_weights(const float* __restrict__ w0,
                                                    const float* __restrict__ cw,
                                                    unsigned short* __restrict__ w0t,
                                                    unsigned short* __restrict__ Mt) {
    int idx = blockIdx.x * 256 + threadIdx.x;
    if (idx < 131072) {
        int n = idx >> 9, k = idx & 511;
        w0t[idx] = f2bf(w0[(size_t)k * 256 + n]);
    } else {
        int j = idx - 131072;
        int l = j >> 16;
        int r = j & 65535;
        int n = r >> 8, k = r & 255;
        float theta = logf(0.5f / (float)(l + 1) + 1.0f);
        float v = theta * cw[(size_t)l * 65536 + (size_t)k * 256 + n];
        if (k == n) v += 1.0f - theta;
        Mt[j] = f2bf(v);
    }
}

// ---------------------------------------------------------------------------
// gemm0: h0 = relu(x @ w0 + b0), bf16 out only.  625 blocks x 4 waves.
// ---------------------------------------------------------------------------
__global__ __launch_bounds__(256) void gemm0_mfma(const unsigned short* __restrict__ xb,
                                                  const unsigned short* __restrict__ w0t,
                                                  const float* __restrict__ b0,
                                                  unsigned short* __restrict__ h0b) {
    int t = threadIdx.x, wv = t >> 6, lane = t & 63;
    int lrow = lane & 15, quad = lane >> 4;
    int r0 = blockIdx.x * 16;

    bf16x8 a[16];
    const unsigned short* arow = xb + (size_t)(r0 + lrow) * NFEAT + quad * 8;
    #pragma unroll
    for (int f = 0; f < 16; ++f)
        a[f] = *(const bf16x8*)(arow + f * 32);

    #pragma unroll 1
    for (int n = 0; n < 4; ++n) {
        int nt = wv * 4 + n;
        floatx4 acc = {0.f, 0.f, 0.f, 0.f};
        const unsigned short* wrow = w0t + (size_t)(nt * 16 + lrow) * NFEAT + quad * 8;
        #pragma unroll
        for (int f = 0; f < 16; ++f) {
            bf16x8 b = *(const bf16x8*)(wrow + f * 32);
            acc = __builtin_amdgcn_mfma_f32_16x16x32_bf16(a[f], b, acc, 0, 0, 0);
        }
        int col = nt * 16 + lrow;
        float bias = b0[col];
        #pragma unroll
        for (int r = 0; r < 4; ++r) {
            int row = r0 + quad * 4 + r;
            h0b[(size_t)row * NHID + col] = f2bf(fmaxf(acc[r] + bias, 0.f));
        }
    }
}

// ---------------------------------------------------------------------------
// layer_fused: block = 16 rows (grid 625), 4 waves.
// Phase 1: sup[i] = 0.9*dinv_i*(dinv_i*h[i] + sum_j dinv_j*h[j]) + 0.1*h0[i]
//          (all-bf16 gathers, fp32 math) -> LDS bf16, padded stride 264.
// Phase 2: out = relu(sup @ M) with M = theta*W + (1-theta)*I (pre-folded).
// LAST: out tile -> LDS fp32, then in-block logits + log_softmax -> out.
// ---------------------------------------------------------------------------
template<bool LAST>
__global__ __launch_bounds__(256) void layer_fused(const unsigned short* __restrict__ hb,
                                                   const unsigned short* __restrict__ h0b,
                                                   const float* __restrict__ dinv,
                                                   const int* __restrict__ cnt,
                                                   const int* __restrict__ ell,
                                                   const unsigned short* __restrict__ Mt,
                                                   const float* __restrict__ w1,
                                                   const float* __restrict__ b1,
                                                   unsigned short* __restrict__ hb_out,
                                                   float* __restrict__ out) {
    __shared__ unsigned short supb[16][264];
    __shared__ int   sj[16][MAXDEG];
    __shared__ float scl[16][MAXDEG];
    __shared__ float hs[LAST ? 16 * 264 : 4];

    int t = threadIdx.x, wv = t >> 6, lane = t & 63;
    int r0 = blockIdx.x * 16;

    // ---- stage neighbor lists for this wave's 4 rows ----
    #pragma unroll
    for (int rr = 0; rr < 4; ++rr) {
        int lr = wv * 4 + rr;
        int i  = r0 + lr;
        int deg = cnt[i];
        for (int e = lane; e < deg; e += 64) {
            int j = ell[(size_t)i * MAXDEG + e];
            sj[lr][e]  = j;
            scl[lr][e] = dinv[j];
        }
    }
    __syncthreads();

    // ---- phase 1: gather + mix -> supb (LDS) ----
    const ushort4v* hv = (const ushort4v*)hb;
    #pragma unroll 1
    for (int rr = 0; rr < 4; ++rr) {
        int lr = wv * 4 + rr;
        int i  = r0 + lr;
        int deg = cnt[i];
        float di = dinv[i];
        ushort4v sv = hv[(size_t)i * 64 + lane];
        float4 acc;
        acc.x = di * bf2f(sv.x);
        acc.y = di * bf2f(sv.y);
        acc.z = di * bf2f(sv.z);
        acc.w = di * bf2f(sv.w);
        #pragma unroll 4
        for (int e = 0; e < deg; ++e) {
            float s = scl[lr][e];
            ushort4v xv = hv[(size_t)sj[lr][e] * 64 + lane];
            acc.x = fmaf(s, bf2f(xv.x), acc.x);
            acc.y = fmaf(s, bf2f(xv.y), acc.y);
            acc.z = fmaf(s, bf2f(xv.z), acc.z);
            acc.w = fmaf(s, bf2f(xv.w), acc.w);
        }
        ushort4v h0v = ((const ushort4v*)h0b)[(size_t)i * 64 + lane];
        ushort4v ob;
        ob.x = f2bf(0.9f * (di * acc.x) + 0.1f * bf2f(h0v.x));
        ob.y = f2bf(0.9f * (di * acc.y) + 0.1f * bf2f(h0v.y));
        ob.z = f2bf(0.9f * (di * acc.z) + 0.1f * bf2f(h0v.z));
        ob.w = f2bf(0.9f * (di * acc.w) + 0.1f * bf2f(h0v.w));
        *(ushort4v*)&supb[lr][4 * lane] = ob;
    }
    __syncthreads();

    // ---- phase 2: MFMA GEMM, epilogue = relu only (residual folded in M) ----
    int lrow = lane & 15, quad = lane >> 4;
    bf16x8 a[8];
    #pragma unroll
    for (int f = 0; f < 8; ++f)
        a[f] = *(const bf16x8*)&supb[lrow][quad * 8 + f * 32];

    #pragma unroll 1
    for (int n = 0; n < 4; ++n) {
        int nt = wv * 4 + n;
        floatx4 acc = {0.f, 0.f, 0.f, 0.f};
        const unsigned short* wrow = Mt + (size_t)(nt * 16 + lrow) * NHID + quad * 8;
        #pragma unroll
        for (int f = 0; f < 8; ++f) {
            bf16x8 b = *(const bf16x8*)(wrow + f * 32);
            acc = __builtin_amdgcn_mfma_f32_16x16x32_bf16(a[f], b, acc, 0, 0, 0);
        }
        int col = nt * 16 + lrow;
        #pragma unroll
        for (int r = 0; r < 4; ++r) {
            int lr2 = quad * 4 + r;
            float o = fmaxf(acc[r], 0.f);
            if (LAST) {
                hs[lr2 * 264 + col] = o;
            } else {
                hb_out[(size_t)(r0 + lr2) * NHID + col] = f2bf(o);
            }
        }
    }

    // ---- phase 3 (LAST only): logits + log_softmax, in-block ----
    if (LAST) {
        __syncthreads();
        #pragma unroll 1
        for (int rr = 0; rr < 4; ++rr) {
            int lr = wv * 4 + rr;
            const float* hr = hs + lr * 264;
            float logit = -1e30f;
            if (lane < NCLASS) {
                float acc = b1[lane];
                #pragma unroll 8
                for (int k = 0; k < NHID; ++k)
                    acc = fmaf(hr[k], w1[k * NCLASS + lane], acc);
                logit = acc;
            }
            float m = logit;
            #pragma unroll
            for (int off = 32; off > 0; off >>= 1)
                m = fmaxf(m, __shfl_xor(m, off, 64));
            float e = (lane < NCLASS) ? expf(logit - m) : 0.0f;
            float ssum = e;
            #pragma unroll
            for (int off = 32; off > 0; off >>= 1)
                ssum += __shfl_xor(ssum, off, 64);
            float lse = m + logf(ssum);
            if (lane < NCLASS)
                out[(size_t)(r0 + lr) * NCLASS + lane] = logit - lse;
        }
    }
}

// ---------------------------------------------------------------------------
extern "C" void kernel_launch(void* const* d_in, const int* in_sizes, int n_in,
                              void* d_out, int out_size, void* d_ws, size_t ws_size,
                              hipStream_t stream) {
    const float* x      = (const float*)d_in[0];
    const float* adj    = (const float*)d_in[1];
    const float* w0     = (const float*)d_in[2];
    const float* b0     = (const float*)d_in[3];
    const float* conv_w = (const float*)d_in[4];
    const float* w1     = (const float*)d_in[5];
    const float* b1     = (const float*)d_in[6];
    float* out = (float*)d_out;

    char* ws = (char*)d_ws;
    size_t off = 0;
    auto alloc = [&](size_t bytes) -> void* {
        void* p = ws + off;
        off = (off + bytes + 255) & ~(size_t)255;
        return p;
    };
    float*          dinv = (float*)alloc((size_t)NN * 4);
    int*            cnt  = (int*)  alloc((size_t)NN * 4);
    int*            ell  = (int*)  alloc((size_t)NN * MAXDEG * 4);
    unsigned short* xb   = (unsigned short*)alloc((size_t)NN * NFEAT * 2);
    unsigned short* w0t  = (unsigned short*)alloc((size_t)NFEAT * NHID * 2);
    unsigned short* Mt   = (unsigned short*)alloc((size_t)NLAYERS * NHID * NHID * 2);
    unsigned short* h0b  = (unsigned short*)alloc((size_t)NN * NHID * 2);
    unsigned short* hPb  = (unsigned short*)alloc((size_t)NN * NHID * 2);
    unsigned short* hQb  = (unsigned short*)alloc((size_t)NN * NHID * 2);

    build_graph<<<NN, 256, 0, stream>>>(adj, cnt, ell, dinv);
    convert_x<<<(NN * NFEAT / 4) / 256, 256, 0, stream>>>(x, xb);
    prep_weights<<<(131072 + NLAYERS * NHID * NHID) / 256, 256, 0, stream>>>(w0, conv_w, w0t, Mt);

    gemm0_mfma<<<NN / 16, 256, 0, stream>>>(xb, w0t, b0, h0b);

    const unsigned short* hcb = h0b;
    for (int l = 0; l < NLAYERS; ++l) {
        unsigned short* nxt = (l & 1) ? hQb : hPb;
        const unsigned short* wt = Mt + (size_t)l * NHID * NHID;
        if (l == NLAYERS - 1)
            layer_fused<true><<<NN / 16, 256, 0, stream>>>(hcb, h0b, dinv, cnt, ell, wt, w1, b1, nullptr, out);
        else
            layer_fused<false><<<NN / 16, 256, 0, stream>>>(hcb, h0b, dinv, cnt, ell, wt, nullptr, nullptr, nxt, nullptr);
        hcb = nxt;
    }
}

// Round 6
// 838.494 us; speedup vs baseline: 1.9705x; 1.0497x over previous
//
#include <hip/hip_runtime.h>
#include <math.h>

#define NN 10000
#define NFEAT 512
#define NHID 256
#define NCLASS 40
#define NLAYERS 8
#define MAXDEG 96

typedef __attribute__((ext_vector_type(8))) short bf16x8;
typedef __attribute__((ext_vector_type(4))) float floatx4;
typedef __attribute__((ext_vector_type(4))) unsigned short ushort4v;

__device__ __forceinline__ unsigned short f2bf(float f) {
    union { float f; unsigned int u; } v; v.f = f;
    unsigned int r = v.u + 0x7fffu + ((v.u >> 16) & 1u);  // RNE
    return (unsigned short)(r >> 16);
}
__device__ __forceinline__ float bf2f(unsigned short h) {
    union { unsigned int u; float f; } v; v.u = ((unsigned int)h) << 16;
    return v.f;
}

// ---------------------------------------------------------------------------
// build_graph: one block per row; one pass over the 400MB dense adjacency.
// ---------------------------------------------------------------------------
__global__ __launch_bounds__(256) void build_graph(const float* __restrict__ adj,
                                                   int* __restrict__ cnt,
                                                   int* __restrict__ ell,
                                                   float* __restrict__ dinv) {
    int i = blockIdx.x;
    __shared__ int scnt;
    if (threadIdx.x == 0) scnt = 0;
    __syncthreads();
    const float4* row = (const float4*)(adj + (size_t)i * NN);
    const int nv = NN / 4;  // 2500
    int* erow = ell + (size_t)i * MAXDEG;
    for (int f = threadIdx.x; f < nv; f += 256) {
        float4 v = row[f];
        if (v.x != 0.0f) { int s = atomicAdd(&scnt, 1); if (s < MAXDEG) erow[s] = 4*f + 0; }
        if (v.y != 0.0f) { int s = atomicAdd(&scnt, 1); if (s < MAXDEG) erow[s] = 4*f + 1; }
        if (v.z != 0.0f) { int s = atomicAdd(&scnt, 1); if (s < MAXDEG) erow[s] = 4*f + 2; }
        if (v.w != 0.0f) { int s = atomicAdd(&scnt, 1); if (s < MAXDEG) erow[s] = 4*f + 3; }
    }
    __syncthreads();
    if (threadIdx.x == 0) {
        int c = scnt;
        cnt[i] = (c < MAXDEG) ? c : MAXDEG;
        dinv[i] = rsqrtf(1.0f + (float)c);
    }
}

// ---------------------------------------------------------------------------
// prep_ell: scl_g[i][e] = dinv[ell[i][e]]  (one-time random gather so the 8
// layer kernels read neighbor scales coalesced).
// ---------------------------------------------------------------------------
__global__ __launch_bounds__(256) void prep_ell(const int* __restrict__ ell,
                                                const int* __restrict__ cnt,
                                                const float* __restrict__ dinv,
                                                float* __restrict__ scl_g) {
    int idx = blockIdx.x * 256 + threadIdx.x;   // 960000 total
    if (idx >= NN * MAXDEG) return;
    int i = idx / MAXDEG, e = idx % MAXDEG;
    float v = 0.0f;
    if (e < cnt[i]) v = dinv[ell[idx]];
    scl_g[idx] = v;
}

// ---------------------------------------------------------------------------
// convert x -> bf16 (4 elements / thread)
// ---------------------------------------------------------------------------
__global__ __launch_bounds__(256) void convert_x(const float* __restrict__ x,
                                                 unsigned short* __restrict__ xb) {
    int idx = blockIdx.x * 256 + threadIdx.x;
    float4 v = ((const float4*)x)[idx];
    ushort4v o;
    o.x = f2bf(v.x); o.y = f2bf(v.y); o.z = f2bf(v.z); o.w = f2bf(v.w);
    ((ushort4v*)xb)[idx] = o;
}

// ---------------------------------------------------------------------------
// prep_weights:
//   w0t[n][k]  = bf16(w0[k][n])                                 (256x512)
//   Mt[l][n][k] = bf16(theta_l * cw[l][k][n] + (1-theta_l)*I)   (fold residual)
// ---------------------------------------------------------------------------
__global__ __launch_bounds__(256) void prep_weights(const float* __restrict__ w0,
                                                    const float* __restrict__ cw,
                                                    unsigned short* __restrict__ w0t,
                                                    unsigned short* __restrict__ Mt) {
    int idx = blockIdx.x * 256 + threadIdx.x;
    if (idx < 131072) {
        int n = idx >> 9, k = idx & 511;
        w0t[idx] = f2bf(w0[(size_t)k * 256 + n]);
    } else {
        int j = idx - 131072;
        int l = j >> 16;
        int r = j & 65535;
        int n = r >> 8, k = r & 255;
        float theta = logf(0.5f / (float)(l + 1) + 1.0f);
        float v = theta * cw[(size_t)l * 65536 + (size_t)k * 256 + n];
        if (k == n) v += 1.0f - theta;
        Mt[j] = f2bf(v);
    }
}

// ---------------------------------------------------------------------------
// gemm0: h0 = relu(x @ w0 + b0), bf16 out.  625 blocks x 8 waves;
// wave = 2 col-tiles of 16.
// ---------------------------------------------------------------------------
__global__ __launch_bounds__(512, 4) void gemm0_mfma(const unsigned short* __restrict__ xb,
                                                     const unsigned short* __restrict__ w0t,
                                                     const float* __restrict__ b0,
                                                     unsigned short* __restrict__ h0b) {
    int t = threadIdx.x, wv = t >> 6, lane = t & 63;
    int lrow = lane & 15, quad = lane >> 4;
    int r0 = blockIdx.x * 16;

    bf16x8 a[16];
    const unsigned short* arow = xb + (size_t)(r0 + lrow) * NFEAT + quad * 8;
    #pragma unroll
    for (int f = 0; f < 16; ++f)
        a[f] = *(const bf16x8*)(arow + f * 32);

    #pragma unroll 1
    for (int n = 0; n < 2; ++n) {
        int nt = wv * 2 + n;
        floatx4 acc = {0.f, 0.f, 0.f, 0.f};
        const unsigned short* wrow = w0t + (size_t)(nt * 16 + lrow) * NFEAT + quad * 8;
        #pragma unroll
        for (int f = 0; f < 16; ++f) {
            bf16x8 b = *(const bf16x8*)(wrow + f * 32);
            acc = __builtin_amdgcn_mfma_f32_16x16x32_bf16(a[f], b, acc, 0, 0, 0);
        }
        int col = nt * 16 + lrow;
        float bias = b0[col];
        #pragma unroll
        for (int r = 0; r < 4; ++r) {
            int row = r0 + quad * 4 + r;
            h0b[(size_t)row * NHID + col] = f2bf(fmaxf(acc[r] + bias, 0.f));
        }
    }
}

// ---------------------------------------------------------------------------
// layer_fused: block = 16 rows (grid 625), 8 waves (512 thr).
// Phase 1: wave handles 2 rows; sup = 0.9*dinv_i*(dinv_i*h[i]+sum dinv_j h[j])
//          + 0.1*h0[i] -> LDS bf16 (stride 264).
// Phase 2: wave handles 2 col-tiles; out = relu(sup @ M), M pre-folded.
// LAST: out tile -> LDS fp32, in-block logits + log_softmax -> out.
// ---------------------------------------------------------------------------
template<bool LAST>
__global__ __launch_bounds__(512, 4) void layer_fused(const unsigned short* __restrict__ hb,
                                                      const unsigned short* __restrict__ h0b,
                                                      const float* __restrict__ dinv,
                                                      const int* __restrict__ cnt,
                                                      const int* __restrict__ ell,
                                                      const float* __restrict__ scl_g,
                                                      const unsigned short* __restrict__ Mt,
                                                      const float* __restrict__ w1,
                                                      const float* __restrict__ b1,
                                                      unsigned short* __restrict__ hb_out,
                                                      float* __restrict__ out) {
    __shared__ unsigned short supb[16][264];
    __shared__ int   sj[16][MAXDEG];
    __shared__ float scl[16][MAXDEG];
    __shared__ float hs[LAST ? 16 * 264 : 4];

    int t = threadIdx.x, wv = t >> 6, lane = t & 63;
    int r0 = blockIdx.x * 16;

    // ---- stage neighbor lists (coalesced; scales precomputed) ----
    #pragma unroll
    for (int rr = 0; rr < 2; ++rr) {
        int lr = wv * 2 + rr;
        int i  = r0 + lr;
        int deg = cnt[i];
        for (int e = lane; e < deg; e += 64) {
            sj[lr][e]  = ell[(size_t)i * MAXDEG + e];
            scl[lr][e] = scl_g[(size_t)i * MAXDEG + e];
        }
    }
    __syncthreads();

    // ---- phase 1: gather + mix -> supb (LDS) ----
    const ushort4v* hv = (const ushort4v*)hb;
    #pragma unroll 1
    for (int rr = 0; rr < 2; ++rr) {
        int lr = wv * 2 + rr;
        int i  = r0 + lr;
        int deg = cnt[i];
        float di = dinv[i];
        ushort4v sv = hv[(size_t)i * 64 + lane];
        float4 acc;
        acc.x = di * bf2f(sv.x);
        acc.y = di * bf2f(sv.y);
        acc.z = di * bf2f(sv.z);
        acc.w = di * bf2f(sv.w);
        #pragma unroll 8
        for (int e = 0; e < deg; ++e) {
            float s = scl[lr][e];
            ushort4v xv = hv[(size_t)sj[lr][e] * 64 + lane];
            acc.x = fmaf(s, bf2f(xv.x), acc.x);
            acc.y = fmaf(s, bf2f(xv.y), acc.y);
            acc.z = fmaf(s, bf2f(xv.z), acc.z);
            acc.w = fmaf(s, bf2f(xv.w), acc.w);
        }
        ushort4v h0v = ((const ushort4v*)h0b)[(size_t)i * 64 + lane];
        ushort4v ob;
        ob.x = f2bf(0.9f * (di * acc.x) + 0.1f * bf2f(h0v.x));
        ob.y = f2bf(0.9f * (di * acc.y) + 0.1f * bf2f(h0v.y));
        ob.z = f2bf(0.9f * (di * acc.z) + 0.1f * bf2f(h0v.z));
        ob.w = f2bf(0.9f * (di * acc.w) + 0.1f * bf2f(h0v.w));
        *(ushort4v*)&supb[lr][4 * lane] = ob;
    }
    __syncthreads();

    // ---- phase 2: MFMA GEMM, epilogue = relu only ----
    int lrow = lane & 15, quad = lane >> 4;
    bf16x8 a[8];
    #pragma unroll
    for (int f = 0; f < 8; ++f)
        a[f] = *(const bf16x8*)&supb[lrow][quad * 8 + f * 32];

    #pragma unroll 1
    for (int n = 0; n < 2; ++n) {
        int nt = wv * 2 + n;
        floatx4 acc = {0.f, 0.f, 0.f, 0.f};
        const unsigned short* wrow = Mt + (size_t)(nt * 16 + lrow) * NHID + quad * 8;
        #pragma unroll
        for (int f = 0; f < 8; ++f) {
            bf16x8 b = *(const bf16x8*)(wrow + f * 32);
            acc = __builtin_amdgcn_mfma_f32_16x16x32_bf16(a[f], b, acc, 0, 0, 0);
        }
        int col = nt * 16 + lrow;
        #pragma unroll
        for (int r = 0; r < 4; ++r) {
            int lr2 = quad * 4 + r;
            float o = fmaxf(acc[r], 0.f);
            if (LAST) {
                hs[lr2 * 264 + col] = o;
            } else {
                hb_out[(size_t)(r0 + lr2) * NHID + col] = f2bf(o);
            }
        }
    }

    // ---- phase 3 (LAST only): logits + log_softmax, in-block ----
    if (LAST) {
        __syncthreads();
        #pragma unroll 1
        for (int rr = 0; rr < 2; ++rr) {
            int lr = wv * 2 + rr;
            const float* hr = hs + lr * 264;
            float logit = -1e30f;
            if (lane < NCLASS) {
                float acc = b1[lane];
                #pragma unroll 8
                for (int k = 0; k < NHID; ++k)
                    acc = fmaf(hr[k], w1[k * NCLASS + lane], acc);
                logit = acc;
            }
            float m = logit;
            #pragma unroll
            for (int off = 32; off > 0; off >>= 1)
                m = fmaxf(m, __shfl_xor(m, off, 64));
            float e = (lane < NCLASS) ? expf(logit - m) : 0.0f;
            float ssum = e;
            #pragma unroll
            for (int off = 32; off > 0; off >>= 1)
                ssum += __shfl_xor(ssum, off, 64);
            float lse = m + logf(ssum);
            if (lane < NCLASS)
                out[(size_t)(r0 + lr) * NCLASS + lane] = logit - lse;
        }
    }
}

// ---------------------------------------------------------------------------
extern "C" void kernel_launch(void* const* d_in, const int* in_sizes, int n_in,
                              void* d_out, int out_size, void* d_ws, size_t ws_size,
                              hipStream_t stream) {
    const float* x      = (const float*)d_in[0];
    const float* adj    = (const float*)d_in[1];
    const float* w0     = (const float*)d_in[2];
    const float* b0     = (const float*)d_in[3];
    const float* conv_w = (const float*)d_in[4];
    const float* w1     = (const float*)d_in[5];
    const float* b1     = (const float*)d_in[6];
    float* out = (float*)d_out;

    char* ws = (char*)d_ws;
    size_t off = 0;
    auto alloc = [&](size_t bytes) -> void* {
        void* p = ws + off;
        off = (off + bytes + 255) & ~(size_t)255;
        return p;
    };
    float*          dinv  = (float*)alloc((size_t)NN * 4);
    int*            cnt   = (int*)  alloc((size_t)NN * 4);
    int*            ell   = (int*)  alloc((size_t)NN * MAXDEG * 4);
    float*          scl_g = (float*)alloc((size_t)NN * MAXDEG * 4);
    unsigned short* xb    = (unsigned short*)alloc((size_t)NN * NFEAT * 2);
    unsigned short* w0t   = (unsigned short*)alloc((size_t)NFEAT * NHID * 2);
    unsigned short* Mt    = (unsigned short*)alloc((size_t)NLAYERS * NHID * NHID * 2);
    unsigned short* h0b   = (unsigned short*)alloc((size_t)NN * NHID * 2);
    unsigned short* hPb   = (unsigned short*)alloc((size_t)NN * NHID * 2);
    unsigned short* hQb   = (unsigned short*)alloc((size_t)NN * NHID * 2);

    build_graph<<<NN, 256, 0, stream>>>(adj, cnt, ell, dinv);
    convert_x<<<(NN * NFEAT / 4) / 256, 256, 0, stream>>>(x, xb);
    prep_weights<<<(131072 + NLAYERS * NHID * NHID) / 256, 256, 0, stream>>>(w0, conv_w, w0t, Mt);
    prep_ell<<<(NN * MAXDEG + 255) / 256, 256, 0, stream>>>(ell, cnt, dinv, scl_g);

    gemm0_mfma<<<NN / 16, 512, 0, stream>>>(xb, w0t, b0, h0b);

    const unsigned short* hcb = h0b;
    for (int l = 0; l < NLAYERS; ++l) {
        unsigned short* nxt = (l & 1) ? hQb : hPb;
        const unsigned short* wt = Mt + (size_t)l * NHID * NHID;
        if (l == NLAYERS - 1)
            layer_fused<true><<<NN / 16, 512, 0, stream>>>(hcb, h0b, dinv, cnt, ell, scl_g, wt, w1, b1, nullptr, out);
        else
            layer_fused<false><<<NN / 16, 512, 0, stream>>>(hcb, h0b, dinv, cnt, ell, scl_g, wt, nullptr, nullptr, nxt, nullptr);
        hcb = nxt;
    }
}

// Round 7
// 838.432 us; speedup vs baseline: 1.9706x; 1.0001x over previous
//
#include <hip/hip_runtime.h>
#include <math.h>

#define NN 10000
#define NFEAT 512
#define NHID 256
#define NCLASS 40
#define NLAYERS 8
#define MAXDEG 96

typedef __attribute__((ext_vector_type(8))) short bf16x8;
typedef __attribute__((ext_vector_type(4))) float floatx4;
typedef __attribute__((ext_vector_type(4))) unsigned short ushort4v;

__device__ __forceinline__ unsigned short f2bf(float f) {
    union { float f; unsigned int u; } v; v.f = f;
    unsigned int r = v.u + 0x7fffu + ((v.u >> 16) & 1u);  // RNE
    return (unsigned short)(r >> 16);
}
__device__ __forceinline__ float bf2f(unsigned short h) {
    union { unsigned int u; float f; } v; v.u = ((unsigned int)h) << 16;
    return v.f;
}

// ---------------------------------------------------------------------------
// build_graph: one block per row; one pass over the 400MB dense adjacency.
// ---------------------------------------------------------------------------
__global__ __launch_bounds__(256) void build_graph(const float* __restrict__ adj,
                                                   int* __restrict__ cnt,
                                                   int* __restrict__ ell,
                                                   float* __restrict__ dinv) {
    int i = blockIdx.x;
    __shared__ int scnt;
    if (threadIdx.x == 0) scnt = 0;
    __syncthreads();
    const float4* row = (const float4*)(adj + (size_t)i * NN);
    const int nv = NN / 4;  // 2500
    int* erow = ell + (size_t)i * MAXDEG;
    for (int f = threadIdx.x; f < nv; f += 256) {
        float4 v = row[f];
        if (v.x != 0.0f) { int s = atomicAdd(&scnt, 1); if (s < MAXDEG) erow[s] = 4*f + 0; }
        if (v.y != 0.0f) { int s = atomicAdd(&scnt, 1); if (s < MAXDEG) erow[s] = 4*f + 1; }
        if (v.z != 0.0f) { int s = atomicAdd(&scnt, 1); if (s < MAXDEG) erow[s] = 4*f + 2; }
        if (v.w != 0.0f) { int s = atomicAdd(&scnt, 1); if (s < MAXDEG) erow[s] = 4*f + 3; }
    }
    __syncthreads();
    if (threadIdx.x == 0) {
        int c = scnt;
        cnt[i] = (c < MAXDEG) ? c : MAXDEG;
        dinv[i] = rsqrtf(1.0f + (float)c);
    }
}

// ---------------------------------------------------------------------------
// prep_ell: scl_g[i][e] = dinv[ell[i][e]] for e<deg, else 0; ell padded with 0
// so the layer gather loop can run in fixed groups of 8 (0-scaled extras).
// ---------------------------------------------------------------------------
__global__ __launch_bounds__(256) void prep_ell(int* __restrict__ ell,
                                                const int* __restrict__ cnt,
                                                const float* __restrict__ dinv,
                                                float* __restrict__ scl_g) {
    int idx = blockIdx.x * 256 + threadIdx.x;   // 960000 total
    if (idx >= NN * MAXDEG) return;
    int i = idx / MAXDEG, e = idx % MAXDEG;
    if (e < cnt[i]) {
        scl_g[idx] = dinv[ell[idx]];
    } else {
        scl_g[idx] = 0.0f;
        ell[idx] = 0;            // safe dummy row, scale 0
    }
}

// ---------------------------------------------------------------------------
// convert x -> bf16 (4 elements / thread)
// ---------------------------------------------------------------------------
__global__ __launch_bounds__(256) void convert_x(const float* __restrict__ x,
                                                 unsigned short* __restrict__ xb) {
    int idx = blockIdx.x * 256 + threadIdx.x;
    float4 v = ((const float4*)x)[idx];
    ushort4v o;
    o.x = f2bf(v.x); o.y = f2bf(v.y); o.z = f2bf(v.z); o.w = f2bf(v.w);
    ((ushort4v*)xb)[idx] = o;
}

// ---------------------------------------------------------------------------
// prep_weights:
//   w0t[n][k]  = bf16(w0[k][n])                                 (256x512)
//   Mt[l][n][k] = bf16(theta_l * cw[l][k][n] + (1-theta_l)*I)   (fold residual)
// ---------------------------------------------------------------------------
__global__ __launch_bounds__(256) void prep_weights(const float* __restrict__ w0,
                                                    const float* __restrict__ cw,
                                                    unsigned short* __restrict__ w0t,
                                                    unsigned short* __restrict__ Mt) {
    int idx = blockIdx.x * 256 + threadIdx.x;
    if (idx < 131072) {
        int n = idx >> 9, k = idx & 511;
        w0t[idx] = f2bf(w0[(size_t)k * 256 + n]);
    } else {
        int j = idx - 131072;
        int l = j >> 16;
        int r = j & 65535;
        int n = r >> 8, k = r & 255;
        float theta = logf(0.5f / (float)(l + 1) + 1.0f);
        float v = theta * cw[(size_t)l * 65536 + (size_t)k * 256 + n];
        if (k == n) v += 1.0f - theta;
        Mt[j] = f2bf(v);
    }
}

// ---------------------------------------------------------------------------
// gemm0: h0 = relu(x @ w0 + b0), bf16 out.  625 blocks x 8 waves;
// wave = 2 col-tiles of 16.
// ---------------------------------------------------------------------------
__global__ __launch_bounds__(512, 4) void gemm0_mfma(const unsigned short* __restrict__ xb,
                                                     const unsigned short* __restrict__ w0t,
                                                     const float* __restrict__ b0,
                                                     unsigned short* __restrict__ h0b) {
    int t = threadIdx.x, wv = t >> 6, lane = t & 63;
    int lrow = lane & 15, quad = lane >> 4;
    int r0 = blockIdx.x * 16;

    bf16x8 a[16];
    const unsigned short* arow = xb + (size_t)(r0 + lrow) * NFEAT + quad * 8;
    #pragma unroll
    for (int f = 0; f < 16; ++f)
        a[f] = *(const bf16x8*)(arow + f * 32);

    #pragma unroll 1
    for (int n = 0; n < 2; ++n) {
        int nt = wv * 2 + n;
        floatx4 acc = {0.f, 0.f, 0.f, 0.f};
        const unsigned short* wrow = w0t + (size_t)(nt * 16 + lrow) * NFEAT + quad * 8;
        #pragma unroll
        for (int f = 0; f < 16; ++f) {
            bf16x8 b = *(const bf16x8*)(wrow + f * 32);
            acc = __builtin_amdgcn_mfma_f32_16x16x32_bf16(a[f], b, acc, 0, 0, 0);
        }
        int col = nt * 16 + lrow;
        float bias = b0[col];
        #pragma unroll
        for (int r = 0; r < 4; ++r) {
            int row = r0 + quad * 4 + r;
            h0b[(size_t)row * NHID + col] = f2bf(fmaxf(acc[r] + bias, 0.f));
        }
    }
}

// ---------------------------------------------------------------------------
// layer_fused: block = 16 rows (grid 625), 8 waves (512 thr), 3 blocks/CU.
// Phase 1: wave handles 2 rows; indices/scales read via SCALAR loads (wave-
//          uniform addresses) so each gather is one independent VMEM load;
//          loop runs in groups of 8 (ell padded, scale 0).
// Phase 2: wave handles 2 col-tiles; out = relu(sup @ M), M pre-folded.
// LAST: out tile -> LDS fp32, in-block logits + log_softmax -> out.
// ---------------------------------------------------------------------------
template<bool LAST>
__global__ __launch_bounds__(512, 6) void layer_fused(const unsigned short* __restrict__ hb,
                                                      const unsigned short* __restrict__ h0b,
                                                      const float* __restrict__ dinv,
                                                      const int* __restrict__ cnt,
                                                      const int* __restrict__ ell,
                                                      const float* __restrict__ scl_g,
                                                      const unsigned short* __restrict__ Mt,
                                                      const float* __restrict__ w1,
                                                      const float* __restrict__ b1,
                                                      unsigned short* __restrict__ hb_out,
                                                      float* __restrict__ out) {
    __shared__ unsigned short supb[16][264];
    __shared__ float hs[LAST ? 16 * 264 : 4];

    int t = threadIdx.x;
    int wv = __builtin_amdgcn_readfirstlane(t >> 6);   // wave-uniform in SGPR
    int lane = t & 63;
    int r0 = blockIdx.x * 16;

    // ---- phase 1: gather + mix -> supb (LDS) ----
    const ushort4v* hv = (const ushort4v*)hb;
    #pragma unroll 1
    for (int rr = 0; rr < 2; ++rr) {
        int lr = wv * 2 + rr;
        int i  = r0 + lr;
        int deg8 = (cnt[i] + 7) & ~7;                  // padded edges are x0.0
        float di = dinv[i];
        const int*   ellrow = ell   + (size_t)i * MAXDEG;
        const float* sclrow = scl_g + (size_t)i * MAXDEG;
        ushort4v sv = hv[(size_t)i * 64 + lane];
        float4 acc;
        acc.x = di * bf2f(sv.x);
        acc.y = di * bf2f(sv.y);
        acc.z = di * bf2f(sv.z);
        acc.w = di * bf2f(sv.w);
        #pragma unroll 1
        for (int e0 = 0; e0 < deg8; e0 += 8) {
            #pragma unroll
            for (int u = 0; u < 8; ++u) {
                int   j = ellrow[e0 + u];              // s_load (uniform)
                float s = sclrow[e0 + u];              // s_load (uniform)
                ushort4v xv = hv[(size_t)j * 64 + lane];
                acc.x = fmaf(s, bf2f(xv.x), acc.x);
                acc.y = fmaf(s, bf2f(xv.y), acc.y);
                acc.z = fmaf(s, bf2f(xv.z), acc.z);
                acc.w = fmaf(s, bf2f(xv.w), acc.w);
            }
        }
        ushort4v h0v = ((const ushort4v*)h0b)[(size_t)i * 64 + lane];
        ushort4v ob;
        ob.x = f2bf(0.9f * (di * acc.x) + 0.1f * bf2f(h0v.x));
        ob.y = f2bf(0.9f * (di * acc.y) + 0.1f * bf2f(h0v.y));
        ob.z = f2bf(0.9f * (di * acc.z) + 0.1f * bf2f(h0v.z));
        ob.w = f2bf(0.9f * (di * acc.w) + 0.1f * bf2f(h0v.w));
        *(ushort4v*)&supb[lr][4 * lane] = ob;
    }
    __syncthreads();

    // ---- phase 2: MFMA GEMM, epilogue = relu only (residual folded in M) ----
    int lrow = lane & 15, quad = lane >> 4;
    bf16x8 a[8];
    #pragma unroll
    for (int f = 0; f < 8; ++f)
        a[f] = *(const bf16x8*)&supb[lrow][quad * 8 + f * 32];

    #pragma unroll 1
    for (int n = 0; n < 2; ++n) {
        int nt = wv * 2 + n;
        floatx4 acc = {0.f, 0.f, 0.f, 0.f};
        const unsigned short* wrow = Mt + (size_t)(nt * 16 + lrow) * NHID + quad * 8;
        #pragma unroll
        for (int f = 0; f < 8; ++f) {
            bf16x8 b = *(const bf16x8*)(wrow + f * 32);
            acc = __builtin_amdgcn_mfma_f32_16x16x32_bf16(a[f], b, acc, 0, 0, 0);
        }
        int col = nt * 16 + lrow;
        #pragma unroll
        for (int r = 0; r < 4; ++r) {
            int lr2 = quad * 4 + r;
            float o = fmaxf(acc[r], 0.f);
            if (LAST) {
                hs[lr2 * 264 + col] = o;
            } else {
                hb_out[(size_t)(r0 + lr2) * NHID + col] = f2bf(o);
            }
        }
    }

    // ---- phase 3 (LAST only): logits + log_softmax, in-block ----
    if (LAST) {
        __syncthreads();
        #pragma unroll 1
        for (int rr = 0; rr < 2; ++rr) {
            int lr = wv * 2 + rr;
            const float* hr = hs + lr * 264;
            float logit = -1e30f;
            if (lane < NCLASS) {
                float acc = b1[lane];
                #pragma unroll 8
                for (int k = 0; k < NHID; ++k)
                    acc = fmaf(hr[k], w1[k * NCLASS + lane], acc);
                logit = acc;
            }
            float m = logit;
            #pragma unroll
            for (int off = 32; off > 0; off >>= 1)
                m = fmaxf(m, __shfl_xor(m, off, 64));
            float e = (lane < NCLASS) ? expf(logit - m) : 0.0f;
            float ssum = e;
            #pragma unroll
            for (int off = 32; off > 0; off >>= 1)
                ssum += __shfl_xor(ssum, off, 64);
            float lse = m + logf(ssum);
            if (lane < NCLASS)
                out[(size_t)(r0 + lr) * NCLASS + lane] = logit - lse;
        }
    }
}

// ---------------------------------------------------------------------------
extern "C" void kernel_launch(void* const* d_in, const int* in_sizes, int n_in,
                              void* d_out, int out_size, void* d_ws, size_t ws_size,
                              hipStream_t stream) {
    const float* x      = (const float*)d_in[0];
    const float* adj    = (const float*)d_in[1];
    const float* w0     = (const float*)d_in[2];
    const float* b0     = (const float*)d_in[3];
    const float* conv_w = (const float*)d_in[4];
    const float* w1     = (const float*)d_in[5];
    const float* b1     = (const float*)d_in[6];
    float* out = (float*)d_out;

    char* ws = (char*)d_ws;
    size_t off = 0;
    auto alloc = [&](size_t bytes) -> void* {
        void* p = ws + off;
        off = (off + bytes + 255) & ~(size_t)255;
        return p;
    };
    float*          dinv  = (float*)alloc((size_t)NN * 4);
    int*            cnt   = (int*)  alloc((size_t)NN * 4);
    int*            ell   = (int*)  alloc((size_t)NN * MAXDEG * 4);
    float*          scl_g = (float*)alloc((size_t)NN * MAXDEG * 4);
    unsigned short* xb    = (unsigned short*)alloc((size_t)NN * NFEAT * 2);
    unsigned short* w0t   = (unsigned short*)alloc((size_t)NFEAT * NHID * 2);
    unsigned short* Mt    = (unsigned short*)alloc((size_t)NLAYERS * NHID * NHID * 2);
    unsigned short* h0b   = (unsigned short*)alloc((size_t)NN * NHID * 2);
    unsigned short* hPb   = (unsigned short*)alloc((size_t)NN * NHID * 2);
    unsigned short* hQb   = (unsigned short*)alloc((size_t)NN * NHID * 2);

    build_graph<<<NN, 256, 0, stream>>>(adj, cnt, ell, dinv);
    convert_x<<<(NN * NFEAT / 4) / 256, 256, 0, stream>>>(x, xb);
    prep_weights<<<(131072 + NLAYERS * NHID * NHID) / 256, 256, 0, stream>>>(w0, conv_w, w0t, Mt);
    prep_ell<<<(NN * MAXDEG + 255) / 256, 256, 0, stream>>>(ell, cnt, dinv, scl_g);

    gemm0_mfma<<<NN / 16, 512, 0, stream>>>(xb, w0t, b0, h0b);

    const unsigned short* hcb = h0b;
    for (int l = 0; l < NLAYERS; ++l) {
        unsigned short* nxt = (l & 1) ? hQb : hPb;
        const unsigned short* wt = Mt + (size_t)l * NHID * NHID;
        if (l == NLAYERS - 1)
            layer_fused<true><<<NN / 16, 512, 0, stream>>>(hcb, h0b, dinv, cnt, ell, scl_g, wt, w1, b1, nullptr, out);
        else
            layer_fused<false><<<NN / 16, 512, 0, stream>>>(hcb, h0b, dinv, cnt, ell, scl_g, wt, nullptr, nullptr, nxt, nullptr);
        hcb = nxt;
    }
}

// Round 8
// 780.677 us; speedup vs baseline: 2.1164x; 1.0740x over previous
//
#include <hip/hip_runtime.h>
#include <math.h>

#define NN 10000
#define NFEAT 512
#define NHID 256
#define NCLASS 40
#define NLAYERS 8
#define MAXDEG 96

typedef __attribute__((ext_vector_type(8))) short bf16x8;
typedef __attribute__((ext_vector_type(4))) float floatx4;
typedef __attribute__((ext_vector_type(2))) float floatx2;
typedef __attribute__((ext_vector_type(4))) unsigned short ushort4v;

__device__ __forceinline__ unsigned short f2bf(float f) {
    union { float f; unsigned int u; } v; v.f = f;
    unsigned int r = v.u + 0x7fffu + ((v.u >> 16) & 1u);  // RNE
    return (unsigned short)(r >> 16);
}
__device__ __forceinline__ float bf2f(unsigned short h) {
    union { unsigned int u; float f; } v; v.u = ((unsigned int)h) << 16;
    return v.f;
}
// fp8 e4m3 (OCP) helpers via HW converters
__device__ __forceinline__ unsigned char f2fp8(float f) {
    return (unsigned char)(__builtin_amdgcn_cvt_pk_fp8_f32(f, f, 0, false) & 0xFF);
}

// ---------------------------------------------------------------------------
// build_graph: one block per row; one pass over the 400MB dense adjacency.
// ---------------------------------------------------------------------------
__global__ __launch_bounds__(256) void build_graph(const float* __restrict__ adj,
                                                   int* __restrict__ cnt,
                                                   int* __restrict__ ell,
                                                   float* __restrict__ dinv) {
    int i = blockIdx.x;
    __shared__ int scnt;
    if (threadIdx.x == 0) scnt = 0;
    __syncthreads();
    const float4* row = (const float4*)(adj + (size_t)i * NN);
    const int nv = NN / 4;  // 2500
    int* erow = ell + (size_t)i * MAXDEG;
    for (int f = threadIdx.x; f < nv; f += 256) {
        float4 v = row[f];
        if (v.x != 0.0f) { int s = atomicAdd(&scnt, 1); if (s < MAXDEG) erow[s] = 4*f + 0; }
        if (v.y != 0.0f) { int s = atomicAdd(&scnt, 1); if (s < MAXDEG) erow[s] = 4*f + 1; }
        if (v.z != 0.0f) { int s = atomicAdd(&scnt, 1); if (s < MAXDEG) erow[s] = 4*f + 2; }
        if (v.w != 0.0f) { int s = atomicAdd(&scnt, 1); if (s < MAXDEG) erow[s] = 4*f + 3; }
    }
    __syncthreads();
    if (threadIdx.x == 0) {
        int c = scnt;
        cnt[i] = (c < MAXDEG) ? c : MAXDEG;
        dinv[i] = rsqrtf(1.0f + (float)c);
    }
}

// ---------------------------------------------------------------------------
// prep_ell: scl_g[i][e] = dinv[ell[i][e]] for e<deg, else 0; ell padded with 0
// so the layer gather loop can run in fixed groups of 8 (0-scaled extras).
// ---------------------------------------------------------------------------
__global__ __launch_bounds__(256) void prep_ell(int* __restrict__ ell,
                                                const int* __restrict__ cnt,
                                                const float* __restrict__ dinv,
                                                float* __restrict__ scl_g) {
    int idx = blockIdx.x * 256 + threadIdx.x;   // 960000 total
    if (idx >= NN * MAXDEG) return;
    int i = idx / MAXDEG, e = idx % MAXDEG;
    if (e < cnt[i]) {
        scl_g[idx] = dinv[ell[idx]];
    } else {
        scl_g[idx] = 0.0f;
        ell[idx] = 0;            // safe dummy row, scale 0
    }
}

// ---------------------------------------------------------------------------
// convert x -> bf16 (4 elements / thread)
// ---------------------------------------------------------------------------
__global__ __launch_bounds__(256) void convert_x(const float* __restrict__ x,
                                                 unsigned short* __restrict__ xb) {
    int idx = blockIdx.x * 256 + threadIdx.x;
    float4 v = ((const float4*)x)[idx];
    ushort4v o;
    o.x = f2bf(v.x); o.y = f2bf(v.y); o.z = f2bf(v.z); o.w = f2bf(v.w);
    ((ushort4v*)xb)[idx] = o;
}

// ---------------------------------------------------------------------------
// convert_h8: bf16 h0 -> fp8 h0 (4 elements / thread, packed uint out)
// ---------------------------------------------------------------------------
__global__ __launch_bounds__(256) void convert_h8(const unsigned short* __restrict__ hb,
                                                  unsigned int* __restrict__ h8) {
    int idx = blockIdx.x * 256 + threadIdx.x;     // 640000 total
    ushort4v v = ((const ushort4v*)hb)[idx];
    unsigned int p = __builtin_amdgcn_cvt_pk_fp8_f32(bf2f(v.x), bf2f(v.y), 0, false);
    p = __builtin_amdgcn_cvt_pk_fp8_f32(bf2f(v.z), bf2f(v.w), p, true);
    h8[idx] = p;
}

// ---------------------------------------------------------------------------
// prep_weights:
//   w0t[n][k]  = bf16(w0[k][n])                                 (256x512)
//   Mt[l][n][k] = bf16(theta_l * cw[l][k][n] + (1-theta_l)*I)   (fold residual)
// ---------------------------------------------------------------------------
__global__ __launch_bounds__(256) void prep_weights(const float* __restrict__ w0,
                                                    const float* __restrict__ cw,
                                                    unsigned short* __restrict__ w0t,
                                                    unsigned short* __restrict__ Mt) {
    int idx = blockIdx.x * 256 + threadIdx.x;
    if (idx < 131072) {
        int n = idx >> 9, k = idx & 511;
        w0t[idx] = f2bf(w0[(size_t)k * 256 + n]);
    } else {
        int j = idx - 131072;
        int l = j >> 16;
        int r = j & 65535;
        int n = r >> 8, k = r & 255;
        float theta = logf(0.5f / (float)(l + 1) + 1.0f);
        float v = theta * cw[(size_t)l * 65536 + (size_t)k * 256 + n];
        if (k == n) v += 1.0f - theta;
        Mt[j] = f2bf(v);
    }
}

// ---------------------------------------------------------------------------
// gemm0: h0 = relu(x @ w0 + b0), bf16 out.  625 blocks x 8 waves;
// wave = 2 col-tiles of 16.
// ---------------------------------------------------------------------------
__global__ __launch_bounds__(512, 4) void gemm0_mfma(const unsigned short* __restrict__ xb,
                                                     const unsigned short* __restrict__ w0t,
                                                     const float* __restrict__ b0,
                                                     unsigned short* __restrict__ h0b) {
    int t = threadIdx.x, wv = t >> 6, lane = t & 63;
    int lrow = lane & 15, quad = lane >> 4;
    int r0 = blockIdx.x * 16;

    bf16x8 a[16];
    const unsigned short* arow = xb + (size_t)(r0 + lrow) * NFEAT + quad * 8;
    #pragma unroll
    for (int f = 0; f < 16; ++f)
        a[f] = *(const bf16x8*)(arow + f * 32);

    #pragma unroll 1
    for (int n = 0; n < 2; ++n) {
        int nt = wv * 2 + n;
        floatx4 acc = {0.f, 0.f, 0.f, 0.f};
        const unsigned short* wrow = w0t + (size_t)(nt * 16 + lrow) * NFEAT + quad * 8;
        #pragma unroll
        for (int f = 0; f < 16; ++f) {
            bf16x8 b = *(const bf16x8*)(wrow + f * 32);
            acc = __builtin_amdgcn_mfma_f32_16x16x32_bf16(a[f], b, acc, 0, 0, 0);
        }
        int col = nt * 16 + lrow;
        float bias = b0[col];
        #pragma unroll
        for (int r = 0; r < 4; ++r) {
            int row = r0 + quad * 4 + r;
            h0b[(size_t)row * NHID + col] = f2bf(fmaxf(acc[r] + bias, 0.f));
        }
    }
}

// ---------------------------------------------------------------------------
// layer_fused: block = 16 rows (grid 625), 8 waves (512 thr).
// Phase 1: wave handles 2 rows; h gathered as fp8 e4m3 (4 B/lane; 256 B/row,
//          2.5 MB working set -> per-XCD-L2 resident); self term fp8 too
//          (coeff ~0.03); h0 residual bf16. fp32 math -> sup bf16 in LDS.
// Phase 2: wave handles 2 col-tiles; out = relu(sup @ M), M pre-folded.
//          Output written as fp8 only (next layer's gathers).
// LAST: out tile -> LDS fp32, in-block logits + log_softmax -> out.
// ---------------------------------------------------------------------------
template<bool LAST>
__global__ __launch_bounds__(512, 6) void layer_fused(const unsigned int* __restrict__ h8,
                                                      const unsigned short* __restrict__ h0b,
                                                      const float* __restrict__ dinv,
                                                      const int* __restrict__ cnt,
                                                      const int* __restrict__ ell,
                                                      const float* __restrict__ scl_g,
                                                      const unsigned short* __restrict__ Mt,
                                                      const float* __restrict__ w1,
                                                      const float* __restrict__ b1,
                                                      unsigned char* __restrict__ h8_out,
                                                      float* __restrict__ out) {
    __shared__ unsigned short supb[16][264];
    __shared__ float hs[LAST ? 16 * 264 : 4];

    int t = threadIdx.x;
    int wv = __builtin_amdgcn_readfirstlane(t >> 6);   // wave-uniform in SGPR
    int lane = t & 63;
    int r0 = blockIdx.x * 16;

    // ---- phase 1: fp8 gather + mix -> supb (LDS) ----
    #pragma unroll 1
    for (int rr = 0; rr < 2; ++rr) {
        int lr = wv * 2 + rr;
        int i  = r0 + lr;
        int deg8 = (cnt[i] + 7) & ~7;                  // padded edges are x0.0
        float di = dinv[i];
        const int*   ellrow = ell   + (size_t)i * MAXDEG;
        const float* sclrow = scl_g + (size_t)i * MAXDEG;
        unsigned int su = h8[(size_t)i * 64 + lane];   // self row (fp8)
        floatx2 slo = __builtin_amdgcn_cvt_pk_f32_fp8(su, false);
        floatx2 shi = __builtin_amdgcn_cvt_pk_f32_fp8(su, true);
        float4 acc;
        acc.x = di * slo.x;
        acc.y = di * slo.y;
        acc.z = di * shi.x;
        acc.w = di * shi.y;
        #pragma unroll 1
        for (int e0 = 0; e0 < deg8; e0 += 8) {
            #pragma unroll
            for (int u = 0; u < 8; ++u) {
                int   j = ellrow[e0 + u];              // uniform -> s_load
                float s = sclrow[e0 + u];
                unsigned int xu = h8[(size_t)j * 64 + lane];
                floatx2 lo = __builtin_amdgcn_cvt_pk_f32_fp8(xu, false);
                floatx2 hi = __builtin_amdgcn_cvt_pk_f32_fp8(xu, true);
                acc.x = fmaf(s, lo.x, acc.x);
                acc.y = fmaf(s, lo.y, acc.y);
                acc.z = fmaf(s, hi.x, acc.z);
                acc.w = fmaf(s, hi.y, acc.w);
            }
        }
        ushort4v h0v = ((const ushort4v*)h0b)[(size_t)i * 64 + lane];
        ushort4v ob;
        ob.x = f2bf(0.9f * (di * acc.x) + 0.1f * bf2f(h0v.x));
        ob.y = f2bf(0.9f * (di * acc.y) + 0.1f * bf2f(h0v.y));
        ob.z = f2bf(0.9f * (di * acc.z) + 0.1f * bf2f(h0v.z));
        ob.w = f2bf(0.9f * (di * acc.w) + 0.1f * bf2f(h0v.w));
        *(ushort4v*)&supb[lr][4 * lane] = ob;
    }
    __syncthreads();

    // ---- phase 2: MFMA GEMM, epilogue = relu only (residual folded in M) ----
    int lrow = lane & 15, quad = lane >> 4;
    bf16x8 a[8];
    #pragma unroll
    for (int f = 0; f < 8; ++f)
        a[f] = *(const bf16x8*)&supb[lrow][quad * 8 + f * 32];

    #pragma unroll 1
    for (int n = 0; n < 2; ++n) {
        int nt = wv * 2 + n;
        floatx4 acc = {0.f, 0.f, 0.f, 0.f};
        const unsigned short* wrow = Mt + (size_t)(nt * 16 + lrow) * NHID + quad * 8;
        #pragma unroll
        for (int f = 0; f < 8; ++f) {
            bf16x8 b = *(const bf16x8*)(wrow + f * 32);
            acc = __builtin_amdgcn_mfma_f32_16x16x32_bf16(a[f], b, acc, 0, 0, 0);
        }
        int col = nt * 16 + lrow;
        #pragma unroll
        for (int r = 0; r < 4; ++r) {
            int lr2 = quad * 4 + r;
            float o = fmaxf(acc[r], 0.f);
            if (LAST) {
                hs[lr2 * 264 + col] = o;
            } else {
                h8_out[(size_t)(r0 + lr2) * NHID + col] = f2fp8(o);
            }
        }
    }

    // ---- phase 3 (LAST only): logits + log_softmax, in-block ----
    if (LAST) {
        __syncthreads();
        #pragma unroll 1
        for (int rr = 0; rr < 2; ++rr) {
            int lr = wv * 2 + rr;
            const float* hr = hs + lr * 264;
            float logit = -1e30f;
            if (lane < NCLASS) {
                float acc = b1[lane];
                #pragma unroll 8
                for (int k = 0; k < NHID; ++k)
                    acc = fmaf(hr[k], w1[k * NCLASS + lane], acc);
                logit = acc;
            }
            float m = logit;
            #pragma unroll
            for (int off = 32; off > 0; off >>= 1)
                m = fmaxf(m, __shfl_xor(m, off, 64));
            float e = (lane < NCLASS) ? expf(logit - m) : 0.0f;
            float ssum = e;
            #pragma unroll
            for (int off = 32; off > 0; off >>= 1)
                ssum += __shfl_xor(ssum, off, 64);
            float lse = m + logf(ssum);
            if (lane < NCLASS)
                out[(size_t)(r0 + lr) * NCLASS + lane] = logit - lse;
        }
    }
}

// ---------------------------------------------------------------------------
extern "C" void kernel_launch(void* const* d_in, const int* in_sizes, int n_in,
                              void* d_out, int out_size, void* d_ws, size_t ws_size,
                              hipStream_t stream) {
    const float* x      = (const float*)d_in[0];
    const float* adj    = (const float*)d_in[1];
    const float* w0     = (const float*)d_in[2];
    const float* b0     = (const float*)d_in[3];
    const float* conv_w = (const float*)d_in[4];
    const float* w1     = (const float*)d_in[5];
    const float* b1     = (const float*)d_in[6];
    float* out = (float*)d_out;

    char* ws = (char*)d_ws;
    size_t off = 0;
    auto alloc = [&](size_t bytes) -> void* {
        void* p = ws + off;
        off = (off + bytes + 255) & ~(size_t)255;
        return p;
    };
    float*          dinv  = (float*)alloc((size_t)NN * 4);
    int*            cnt   = (int*)  alloc((size_t)NN * 4);
    int*            ell   = (int*)  alloc((size_t)NN * MAXDEG * 4);
    float*          scl_g = (float*)alloc((size_t)NN * MAXDEG * 4);
    unsigned short* xb    = (unsigned short*)alloc((size_t)NN * NFEAT * 2);
    unsigned short* w0t   = (unsigned short*)alloc((size_t)NFEAT * NHID * 2);
    unsigned short* Mt    = (unsigned short*)alloc((size_t)NLAYERS * NHID * NHID * 2);
    unsigned short* h0b   = (unsigned short*)alloc((size_t)NN * NHID * 2);
    unsigned int*   h08   = (unsigned int*)alloc((size_t)NN * NHID);
    unsigned int*   hP8   = (unsigned int*)alloc((size_t)NN * NHID);
    unsigned int*   hQ8   = (unsigned int*)alloc((size_t)NN * NHID);

    build_graph<<<NN, 256, 0, stream>>>(adj, cnt, ell, dinv);
    convert_x<<<(NN * NFEAT / 4) / 256, 256, 0, stream>>>(x, xb);
    prep_weights<<<(131072 + NLAYERS * NHID * NHID) / 256, 256, 0, stream>>>(w0, conv_w, w0t, Mt);
    prep_ell<<<(NN * MAXDEG + 255) / 256, 256, 0, stream>>>(ell, cnt, dinv, scl_g);

    gemm0_mfma<<<NN / 16, 512, 0, stream>>>(xb, w0t, b0, h0b);
    convert_h8<<<(NN * NHID / 4) / 256, 256, 0, stream>>>(h0b, h08);

    const unsigned int* hc8 = h08;
    for (int l = 0; l < NLAYERS; ++l) {
        unsigned int* nxt = (l & 1) ? hQ8 : hP8;
        const unsigned short* wt = Mt + (size_t)l * NHID * NHID;
        if (l == NLAYERS - 1)
            layer_fused<true><<<NN / 16, 512, 0, stream>>>(hc8, h0b, dinv, cnt, ell, scl_g, wt, w1, b1, nullptr, out);
        else
            layer_fused<false><<<NN / 16, 512, 0, stream>>>(hc8, h0b, dinv, cnt, ell, scl_g, wt, nullptr, nullptr, (unsigned char*)nxt, nullptr);
        hc8 = nxt;
    }
}